// Round 8
// baseline (5547.333 us; speedup 1.0000x reference)
//
#include <hip/hip_runtime.h>

typedef __attribute__((ext_vector_type(8))) short bf16x8;
typedef __attribute__((ext_vector_type(4))) float f32x4;

#define NB 16384
#define NK 2048
#define ND 1000
#define KP 1024            // padded K
#define NCHK 1024          // sweep blocks == partial chunks

__device__ float  g_dist[(size_t)NB * NK];          // 128 MiB
__device__ ushort g_E[(size_t)NB * NK];             // 64 MiB fp16 e' = exp(-2d)*8192
__device__ ushort g_Fh[(size_t)NB * KP], g_Fl[(size_t)NB * KP];   // pre-swizzled
__device__ ushort g_Ch[(size_t)NK * KP], g_Cl[(size_t)NK * KP];
__device__ float  g_u[NK], g_c2[NK];
__device__ float  g_f2[NB], g_bd[NB];
__device__ float  g_part[(size_t)NCHK * NK];        // 8 MiB
__device__ int    g_cc[NK], g_rc[NK];
// hierarchical grid barrier state (.bss zero-init; count fields return to 0)
__device__ uint   g_bloc[16 * 16];                  // one counter per 64B line
__device__ uint   g_bmid, g_bgen;

typedef const __attribute__((address_space(1))) void gvoid_t;
typedef __attribute__((address_space(3))) void lvoid_t;

union h16 { ushort u; _Float16 h; };

__device__ __forceinline__ ushort bf16_rne(float x){
    uint u = __float_as_uint(x);
    uint lsb = (u >> 16) & 1u;
    u += 0x7fffu + lsb;
    return (ushort)(u >> 16);
}
__device__ __forceinline__ float bf16_to_f(ushort h){
    return __uint_as_float(((uint)h) << 16);
}
__device__ __forceinline__ float aload(const float* p){
    return __hip_atomic_load(p, __ATOMIC_RELAXED, __HIP_MEMORY_SCOPE_AGENT);
}
__device__ __forceinline__ void astore(float* p, float v){
    __hip_atomic_store(p, v, __ATOMIC_RELAXED, __HIP_MEMORY_SCOPE_AGENT);
}

// hierarchical sense-reversing grid barrier (all 1024 blocks co-resident)
__device__ __forceinline__ void grid_sync(){
    __syncthreads();
    if (threadIdx.x == 0){
        __threadfence();
        uint gen = __hip_atomic_load(&g_bgen, __ATOMIC_RELAXED, __HIP_MEMORY_SCOPE_AGENT);
        uint grp = blockIdx.x >> 6;    // 16 groups of 64 blocks
        uint prev = __hip_atomic_fetch_add(&g_bloc[grp * 16], 1u, __ATOMIC_ACQ_REL, __HIP_MEMORY_SCOPE_AGENT);
        if (prev == 63){
            __hip_atomic_store(&g_bloc[grp * 16], 0u, __ATOMIC_RELAXED, __HIP_MEMORY_SCOPE_AGENT);
            uint pm = __hip_atomic_fetch_add(&g_bmid, 1u, __ATOMIC_ACQ_REL, __HIP_MEMORY_SCOPE_AGENT);
            if (pm == 15){
                __hip_atomic_store(&g_bmid, 0u, __ATOMIC_RELAXED, __HIP_MEMORY_SCOPE_AGENT);
                __hip_atomic_fetch_add(&g_bgen, 1u, __ATOMIC_ACQ_REL, __HIP_MEMORY_SCOPE_AGENT);
            }
        }
        while (__hip_atomic_load(&g_bgen, __ATOMIC_ACQUIRE, __HIP_MEMORY_SCOPE_AGENT) == gen)
            __builtin_amdgcn_s_sleep(8);
        __threadfence();
    }
    __syncthreads();
}

// ---------------- prep: fp32 -> (hi,lo) bf16 split, K-pad, XOR-swizzle, row-sumsq ----------------
template<int WHICH>
__global__ __launch_bounds__(256) void cn_prep(const float* __restrict__ X){
    ushort* __restrict__ H = WHICH ? g_Ch : g_Fh;
    ushort* __restrict__ L = WHICH ? g_Cl : g_Fl;
    float*  __restrict__ sq = WHICH ? g_c2 : g_f2;
    const int row = blockIdx.x, t = threadIdx.x;
    const int lane = t & 63, wid = t >> 6;
    float4 x = make_float4(0.f,0.f,0.f,0.f);
    if (t < 250) x = *(const float4*)(X + (size_t)row * ND + 4 * t);
    double s = (double)x.x*x.x + (double)x.y*x.y + (double)x.z*x.z + (double)x.w*x.w;
    ushort4 h4, l4;
#pragma unroll
    for (int c = 0; c < 4; ++c){
        float xc = (&x.x)[c];
        ushort h = bf16_rne(xc);
        (&h4.x)[c] = h;
        (&l4.x)[c] = bf16_rne(xc - bf16_to_f(h));
    }
    const int base = (t >> 3) << 5;
    const int grp  = (t >> 1) & 3;
    const int pos  = base + ((grp ^ ((row >> 1) & 3)) << 3) + ((4 * t) & 7);
    *(ushort4*)&H[(size_t)row * KP + pos] = h4;
    *(ushort4*)&L[(size_t)row * KP + pos] = l4;

    __shared__ double pr[4];
    for (int off = 32; off; off >>= 1) s += __shfl_xor(s, off);
    if (lane == 0) pr[wid] = s;
    __syncthreads();
    if (t == 0) sq[row] = (float)(pr[0] + pr[1] + pr[2] + pr[3]);
}

// ---------------- split-bf16 MFMA distance GEMM, global_load_lds staging ----------------
__global__ __launch_bounds__(256) void cn_gemm_dist(){
    __shared__ __attribute__((aligned(16))) ushort Ah[128 * 32];
    __shared__ __attribute__((aligned(16))) ushort Al[128 * 32];
    __shared__ __attribute__((aligned(16))) ushort Bh[128 * 32];
    __shared__ __attribute__((aligned(16))) ushort Bl[128 * 32];

    const int tid = threadIdx.x;
    const int lane = tid & 63, wid = tid >> 6;
    const int wr = wid >> 1, wc = wid & 1;
    const int brow0 = blockIdx.y * 128, bcol0 = blockIdx.x * 128;

    f32x4 acc[4][4];
#pragma unroll
    for (int m = 0; m < 4; ++m)
#pragma unroll
        for (int n = 0; n < 4; ++n) acc[m][n] = (f32x4){0.f,0.f,0.f,0.f};

    const int lrow = lane >> 2;
    const int lcol = (lane & 3) * 8;

    for (int step = 0; step < 32; ++step){
        const int k0 = step * 32;
#pragma unroll
        for (int i = 0; i < 2; ++i){
            const int ch = wid * 2 + i;
            const int ldso = ch * 512;
            const size_t ga = ((size_t)(brow0 + ch * 16 + lrow)) * KP + k0 + lcol;
            const size_t gb = ((size_t)(bcol0 + ch * 16 + lrow)) * KP + k0 + lcol;
            __builtin_amdgcn_global_load_lds((gvoid_t*)(g_Fh + ga), (lvoid_t*)(Ah + ldso), 16, 0, 0);
            __builtin_amdgcn_global_load_lds((gvoid_t*)(g_Fl + ga), (lvoid_t*)(Al + ldso), 16, 0, 0);
            __builtin_amdgcn_global_load_lds((gvoid_t*)(g_Ch + gb), (lvoid_t*)(Bh + ldso), 16, 0, 0);
            __builtin_amdgcn_global_load_lds((gvoid_t*)(g_Cl + gb), (lvoid_t*)(Bl + ldso), 16, 0, 0);
        }
        __syncthreads();

        const int arow = wr * 64 + (lane & 15);
        const int brow = wc * 64 + (lane & 15);
        const int kof  = (((lane >> 4) ^ ((lane >> 1) & 3)) * 8);
        bf16x8 afh[4], afl[4], bfh[4], bfl[4];
#pragma unroll
        for (int m = 0; m < 4; ++m){
            afh[m] = *(const bf16x8*)&Ah[(arow + m * 16) * 32 + kof];
            afl[m] = *(const bf16x8*)&Al[(arow + m * 16) * 32 + kof];
        }
#pragma unroll
        for (int n = 0; n < 4; ++n){
            bfh[n] = *(const bf16x8*)&Bh[(brow + n * 16) * 32 + kof];
            bfl[n] = *(const bf16x8*)&Bl[(brow + n * 16) * 32 + kof];
        }
#pragma unroll
        for (int m = 0; m < 4; ++m)
#pragma unroll
            for (int n = 0; n < 4; ++n){
                acc[m][n] = __builtin_amdgcn_mfma_f32_16x16x32_bf16(afh[m], bfh[n], acc[m][n], 0, 0, 0);
                acc[m][n] = __builtin_amdgcn_mfma_f32_16x16x32_bf16(afh[m], bfl[n], acc[m][n], 0, 0, 0);
                acc[m][n] = __builtin_amdgcn_mfma_f32_16x16x32_bf16(afl[m], bfh[n], acc[m][n], 0, 0, 0);
            }
        __syncthreads();
    }

#pragma unroll
    for (int m = 0; m < 4; ++m){
        int rowb = brow0 + wr * 64 + m * 16 + (lane >> 4) * 4;
#pragma unroll
        for (int n = 0; n < 4; ++n){
            int col = bcol0 + wc * 64 + n * 16 + (lane & 15);
            float c2v = g_c2[col];
#pragma unroll
            for (int j = 0; j < 4; ++j){
                float d2 = g_f2[rowb + j] + c2v - 2.0f * acc[m][n][j];
                float d  = sqrtf(fmaxf(d2, 0.0f));
                size_t idx = (size_t)(rowb + j) * NK + col;
                g_dist[idx] = d;
                h16 cv; cv.h = (_Float16)(__expf(-2.0f * d) * 8192.0f);
                g_E[idx] = cv.u;
            }
        }
    }
}

// ---------------- persistent sinkhorn iterations 0..14 (no argmax path) ----------------
// it 0: fp16-e, u==1, cst=1; it 1..9: fp16-e; it 10..14: fp32 exact tail.
// 1024 blocks x 256 thr, forced 4 blocks/CU co-residency via launch_bounds.
__global__ __launch_bounds__(256, 4) void cn_sink15(){
    const int lane = threadIdx.x & 63, wid = threadIdx.x >> 6;
    const int gtid = blockIdx.x * 256 + (int)threadIdx.x;
    const int b0 = blockIdx.x * 16 + wid * 4;

    if (gtid < NK){ g_cc[gtid] = 0; g_rc[gtid] = 0; }

    __shared__ float4 sred[3][8][64];

    for (int it = 0; it < 15; ++it){
        const bool useW = (it >= 1);
        const bool f16  = (it <= 9);
        const float cst = (it == 0) ? 1.0f : (1.0f / (float)NB);

        float4 uu[8];
        if (useW){
#pragma unroll
            for (int j = 0; j < 8; ++j)
#pragma unroll
                for (int c = 0; c < 4; ++c)
                    (&uu[j].x)[c] = aload(&g_u[4 * lane + 256 * j + c]);
        }

        float4 S[8];
#pragma unroll
        for (int j = 0; j < 8; ++j) S[j] = make_float4(0.f,0.f,0.f,0.f);

        for (int r = 0; r < 4; ++r){
            const int b = b0 + r;
            float tsum = 0.f;
            if (f16){
                ushort4 q4[8];
                const ushort* er = g_E + (size_t)b * NK + 4 * lane;
#pragma unroll
                for (int j = 0; j < 8; ++j){
                    q4[j] = *(const ushort4*)(er + 256 * j);
#pragma unroll
                    for (int c = 0; c < 4; ++c){
                        h16 cv; cv.u = (&q4[j].x)[c];
                        float e = (float)cv.h;
                        tsum += useW ? e * (&uu[j].x)[c] : e;
                    }
                }
#pragma unroll
                for (int off = 32; off; off >>= 1) tsum += __shfl_xor(tsum, off);
                const float v = cst / tsum;
#pragma unroll
                for (int j = 0; j < 8; ++j){
#pragma unroll
                    for (int c = 0; c < 4; ++c){
                        h16 cv; cv.u = (&q4[j].x)[c];
                        (&S[j].x)[c] += (float)cv.h * v;
                    }
                }
            } else {
                float4 ev[8];
                const float* dr = g_dist + (size_t)b * NK + 4 * lane;
#pragma unroll
                for (int j = 0; j < 8; ++j){
                    float4 d4 = *(const float4*)(dr + 256 * j);
#pragma unroll
                    for (int c = 0; c < 4; ++c){
                        float e = __expf(-2.0f * (&d4.x)[c]);
                        (&ev[j].x)[c] = e;
                        tsum += e * (&uu[j].x)[c];
                    }
                }
#pragma unroll
                for (int off = 32; off; off >>= 1) tsum += __shfl_xor(tsum, off);
                const float v = cst / tsum;
#pragma unroll
                for (int j = 0; j < 8; ++j){
                    S[j].x += ev[j].x * v; S[j].y += ev[j].y * v;
                    S[j].z += ev[j].z * v; S[j].w += ev[j].w * v;
                }
            }
        }

        // cross-wave reduce -> block partial
        if (wid > 0){
#pragma unroll
            for (int j = 0; j < 8; ++j) sred[wid - 1][j][lane] = S[j];
        }
        __syncthreads();
        if (wid == 0){
#pragma unroll
            for (int w = 0; w < 3; ++w)
#pragma unroll
                for (int j = 0; j < 8; ++j){
                    float4 o = sred[w][j][lane];
                    S[j].x += o.x; S[j].y += o.y; S[j].z += o.z; S[j].w += o.w;
                }
#pragma unroll
            for (int j = 0; j < 8; ++j)
#pragma unroll
                for (int c = 0; c < 4; ++c)
                    astore(&g_part[(size_t)blockIdx.x * NK + 4 * lane + 256 * j + c], (&S[j].x)[c]);
        }
        grid_sync();

        // reduce phase: waves 0,1 -> k = 2*bid + wid; fixed-order fp64 + butterfly
        if (wid < 2){
            const int k = blockIdx.x * 2 + wid;
            double s = 0.0;
#pragma unroll
            for (int i = 0; i < 16; ++i)
                s += (double)aload(&g_part[(size_t)(lane * 16 + i) * NK + k]);
            s += __shfl_xor(s, 32); s += __shfl_xor(s, 16); s += __shfl_xor(s, 8);
            s += __shfl_xor(s, 4);  s += __shfl_xor(s, 2);  s += __shfl_xor(s, 1);
            if (lane == 0) astore(&g_u[k], (float)((1.0 / (double)NK) / s));
        }
        grid_sync();
    }
}

// ---------------- final sweep: v from u_15, S -> partials; argmax/argmin/loss ----------------
__global__ __launch_bounds__(256) void cn_sweep_fin(float* __restrict__ outba){
    __shared__ float4 sred[3][8][64];
    const int lane = threadIdx.x & 63, wid = threadIdx.x >> 6;
    const int row0 = (blockIdx.x * 4 + wid) * 4;
    const float cst = 1.0f / (float)NB;

    float4 uu[8], ak[8];
#pragma unroll
    for (int j = 0; j < 8; ++j)
        uu[j] = *(const float4*)&g_u[4 * lane + 256 * j];
#pragma unroll
    for (int j = 0; j < 8; ++j)
#pragma unroll
        for (int c = 0; c < 4; ++c)
            (&ak[j].x)[c] = (float)log((double)(&uu[j].x)[c] * (double)NK);

    float4 S[8];
#pragma unroll
    for (int j = 0; j < 8; ++j) S[j] = make_float4(0.f,0.f,0.f,0.f);

    for (int r = 0; r < 4; ++r){
        const int b = row0 + r;
        float4 ev[8], dv[8];
        float tsum = 0.f;
        const float* dr = g_dist + (size_t)b * NK + 4 * lane;
#pragma unroll
        for (int j = 0; j < 8; ++j){
            float4 d4 = *(const float4*)(dr + 256 * j);
#pragma unroll
            for (int c = 0; c < 4; ++c){
                float e = __expf(-2.0f * (&d4.x)[c]);
                (&ev[j].x)[c] = e;
                tsum += e * (&uu[j].x)[c];
            }
            dv[j] = d4;
        }
#pragma unroll
        for (int off = 32; off; off >>= 1) tsum += __shfl_xor(tsum, off);
        const float v = cst / tsum;
#pragma unroll
        for (int j = 0; j < 8; ++j){
            S[j].x += ev[j].x * v; S[j].y += ev[j].y * v;
            S[j].z += ev[j].z * v; S[j].w += ev[j].w * v;
        }

        double bestT = -1.0e300; int bi = 0; float bd = 0.f;
        float rbest = 3.4e38f;   int ri = 0;
#pragma unroll
        for (int j = 0; j < 8; ++j){
#pragma unroll
            for (int c = 0; c < 4; ++c){
                int k = 256 * j + 4 * lane + c;
                float d = (&dv[j].x)[c];
                double t = 2.0 * (double)d - (double)(&ak[j].x)[c];
                if (t > bestT){ bestT = t; bi = k; bd = d; }
                if (d < rbest){ rbest = d; ri = k; }
            }
        }
        for (int off = 32; off; off >>= 1){
            double oT = __shfl_xor(bestT, off);
            int    oi = __shfl_xor(bi, off);
            float  od = __shfl_xor(bd, off);
            if (oT > bestT || (oT == bestT && oi < bi)){ bestT = oT; bi = oi; bd = od; }
            float orb = __shfl_xor(rbest, off);
            int   ori = __shfl_xor(ri, off);
            if (orb < rbest || (orb == rbest && ori < ri)){ rbest = orb; ri = ori; }
        }
        if (lane == 0){
            outba[b] = (float)bi;
            g_bd[b] = bd;
            atomicAdd(&g_cc[bi], 1);
            atomicAdd(&g_rc[ri], 1);
        }
    }

    if (wid > 0){
#pragma unroll
        for (int j = 0; j < 8; ++j) sred[wid - 1][j][lane] = S[j];
    }
    __syncthreads();
    if (wid == 0){
#pragma unroll
        for (int w = 0; w < 3; ++w)
#pragma unroll
            for (int j = 0; j < 8; ++j){
                float4 o = sred[w][j][lane];
                S[j].x += o.x; S[j].y += o.y; S[j].z += o.z; S[j].w += o.w;
            }
#pragma unroll
        for (int j = 0; j < 8; ++j)
            *(float4*)&g_part[(size_t)blockIdx.x * NK + 4 * lane + 256 * j] = S[j];
    }
}

// scnt[k] = B*u[k]*S_k  (fixed-order fp64)
__global__ __launch_bounds__(256) void cn_red_fin(float* __restrict__ out){
    __shared__ double red[4][64];
    const int lane = threadIdx.x & 63, q = threadIdx.x >> 6;
    const int k = blockIdx.x * 64 + lane;
    double s = 0.0;
    for (int ch = q * 256; ch < q * 256 + 256; ++ch)
        s += (double)g_part[(size_t)ch * NK + k];
    red[q][lane] = s;
    __syncthreads();
    if (q == 0){
        double tot = red[0][lane] + red[1][lane] + red[2][lane] + red[3][lane];
        out[1 + NB + k] = (float)((double)NB * (double)g_u[k] * tot);
    }
}

__global__ __launch_bounds__(256) void cn_finalize(float* __restrict__ out){
    int i = blockIdx.x * 256 + threadIdx.x;
    if (i < NK){
        out[1 + NB + NK + i]       = (float)g_cc[i];
        out[1 + NB + 2 * NK + i]   = (float)g_rc[i];
    }
    if (blockIdx.x == 0){
        __shared__ double red[4];
        int lane = threadIdx.x & 63, wid = threadIdx.x >> 6;
        double s = 0.0;
        for (int b = threadIdx.x; b < NB; b += 256) s += (double)g_bd[b];
        for (int off = 32; off; off >>= 1) s += __shfl_xor(s, off);
        if (lane == 0) red[wid] = s;
        __syncthreads();
        if (threadIdx.x == 0)
            out[0] = (float)((red[0] + red[1] + red[2] + red[3]) / (double)NB);
    }
}

extern "C" void kernel_launch(void* const* d_in, const int* in_sizes, int n_in,
                              void* d_out, int out_size, void* d_ws, size_t ws_size,
                              hipStream_t stream){
    const float* F  = (const float*)d_in[0];
    const float* Cn = (const float*)d_in[1];
    float* out = (float*)d_out;
    (void)d_ws; (void)ws_size;

    cn_prep<0><<<NB, 256, 0, stream>>>(F);
    cn_prep<1><<<NK, 256, 0, stream>>>(Cn);

    dim3 gg(NK / 128, NB / 128);
    cn_gemm_dist<<<gg, 256, 0, stream>>>();

    cn_sink15<<<NCHK, 256, 0, stream>>>();

    cn_sweep_fin<<<NCHK, 256, 0, stream>>>(out + 1);
    cn_red_fin<<<NK / 64, 256, 0, stream>>>(out);
    cn_finalize<<<NK / 256, 256, 0, stream>>>(out);
}

// Round 9
// 4938.587 us; speedup vs baseline: 1.1233x; 1.1233x over previous
//
#include <hip/hip_runtime.h>

typedef __attribute__((ext_vector_type(8))) short bf16x8;
typedef __attribute__((ext_vector_type(4))) float f32x4;

#define NB 16384
#define NK 2048
#define ND 1000
#define KP 1024            // padded K
#define NCHK 1024          // sweep blocks == partial chunks

__device__ float  g_dist[(size_t)NB * NK];          // 128 MiB
__device__ ushort g_E[(size_t)NB * NK];             // 64 MiB fp16 e' = exp(-2d)*8192
__device__ ushort g_Fh[(size_t)NB * KP], g_Fl[(size_t)NB * KP];   // pre-swizzled
__device__ ushort g_Ch[(size_t)NK * KP], g_Cl[(size_t)NK * KP];
__device__ float  g_u[NK], g_c2[NK];
__device__ float  g_f2[NB], g_bd[NB];
__device__ float  g_part[(size_t)NCHK * NK];        // 8 MiB
__device__ int    g_cc[NK], g_rc[NK];
// hierarchical grid barrier state (.bss zero-init; counters return to 0)
__device__ uint   g_bloc[16 * 16];                  // one counter per 64B line
__device__ uint   g_bmid, g_bgen;

typedef const __attribute__((address_space(1))) void gvoid_t;
typedef __attribute__((address_space(3))) void lvoid_t;

union h16 { ushort u; _Float16 h; };

__device__ __forceinline__ ushort bf16_rne(float x){
    uint u = __float_as_uint(x);
    uint lsb = (u >> 16) & 1u;
    u += 0x7fffu + lsb;
    return (ushort)(u >> 16);
}
__device__ __forceinline__ float bf16_to_f(ushort h){
    return __uint_as_float(((uint)h) << 16);
}

// hierarchical sense-reversing grid barrier (all 1024 blocks co-resident).
// Data coherence: __threadfence() = agent-scope fence (L2 writeback on release
// side, L1/L2 invalidate on acquire side) -> plain cached loads/stores are
// valid for cross-block data. Atomics ONLY for the barrier protocol.
__device__ __forceinline__ void grid_sync(){
    __syncthreads();
    if (threadIdx.x == 0){
        __threadfence();    // release: flush this block's stores toward LLC
        uint gen = __hip_atomic_load(&g_bgen, __ATOMIC_RELAXED, __HIP_MEMORY_SCOPE_AGENT);
        uint grp = blockIdx.x >> 6;    // 16 groups of 64 blocks
        uint prev = __hip_atomic_fetch_add(&g_bloc[grp * 16], 1u, __ATOMIC_ACQ_REL, __HIP_MEMORY_SCOPE_AGENT);
        if (prev == 63){
            __hip_atomic_store(&g_bloc[grp * 16], 0u, __ATOMIC_RELAXED, __HIP_MEMORY_SCOPE_AGENT);
            uint pm = __hip_atomic_fetch_add(&g_bmid, 1u, __ATOMIC_ACQ_REL, __HIP_MEMORY_SCOPE_AGENT);
            if (pm == 15){
                __hip_atomic_store(&g_bmid, 0u, __ATOMIC_RELAXED, __HIP_MEMORY_SCOPE_AGENT);
                __hip_atomic_fetch_add(&g_bgen, 1u, __ATOMIC_ACQ_REL, __HIP_MEMORY_SCOPE_AGENT);
            }
        }
        while (__hip_atomic_load(&g_bgen, __ATOMIC_ACQUIRE, __HIP_MEMORY_SCOPE_AGENT) == gen)
            __builtin_amdgcn_s_sleep(2);
        __threadfence();    // acquire: invalidate stale L1/L2 before plain reads
    }
    __syncthreads();
}

// ---------------- prep: fp32 -> (hi,lo) bf16 split, K-pad, XOR-swizzle, row-sumsq ----------------
template<int WHICH>
__global__ __launch_bounds__(256) void cn_prep(const float* __restrict__ X){
    ushort* __restrict__ H = WHICH ? g_Ch : g_Fh;
    ushort* __restrict__ L = WHICH ? g_Cl : g_Fl;
    float*  __restrict__ sq = WHICH ? g_c2 : g_f2;
    const int row = blockIdx.x, t = threadIdx.x;
    const int lane = t & 63, wid = t >> 6;
    float4 x = make_float4(0.f,0.f,0.f,0.f);
    if (t < 250) x = *(const float4*)(X + (size_t)row * ND + 4 * t);
    double s = (double)x.x*x.x + (double)x.y*x.y + (double)x.z*x.z + (double)x.w*x.w;
    ushort4 h4, l4;
#pragma unroll
    for (int c = 0; c < 4; ++c){
        float xc = (&x.x)[c];
        ushort h = bf16_rne(xc);
        (&h4.x)[c] = h;
        (&l4.x)[c] = bf16_rne(xc - bf16_to_f(h));
    }
    const int base = (t >> 3) << 5;
    const int grp  = (t >> 1) & 3;
    const int pos  = base + ((grp ^ ((row >> 1) & 3)) << 3) + ((4 * t) & 7);
    *(ushort4*)&H[(size_t)row * KP + pos] = h4;
    *(ushort4*)&L[(size_t)row * KP + pos] = l4;

    __shared__ double pr[4];
    for (int off = 32; off; off >>= 1) s += __shfl_xor(s, off);
    if (lane == 0) pr[wid] = s;
    __syncthreads();
    if (t == 0) sq[row] = (float)(pr[0] + pr[1] + pr[2] + pr[3]);
}

// ---------------- split-bf16 MFMA distance GEMM, global_load_lds staging ----------------
__global__ __launch_bounds__(256) void cn_gemm_dist(){
    __shared__ __attribute__((aligned(16))) ushort Ah[128 * 32];
    __shared__ __attribute__((aligned(16))) ushort Al[128 * 32];
    __shared__ __attribute__((aligned(16))) ushort Bh[128 * 32];
    __shared__ __attribute__((aligned(16))) ushort Bl[128 * 32];

    const int tid = threadIdx.x;
    const int lane = tid & 63, wid = tid >> 6;
    const int wr = wid >> 1, wc = wid & 1;
    const int brow0 = blockIdx.y * 128, bcol0 = blockIdx.x * 128;

    f32x4 acc[4][4];
#pragma unroll
    for (int m = 0; m < 4; ++m)
#pragma unroll
        for (int n = 0; n < 4; ++n) acc[m][n] = (f32x4){0.f,0.f,0.f,0.f};

    const int lrow = lane >> 2;
    const int lcol = (lane & 3) * 8;

    for (int step = 0; step < 32; ++step){
        const int k0 = step * 32;
#pragma unroll
        for (int i = 0; i < 2; ++i){
            const int ch = wid * 2 + i;
            const int ldso = ch * 512;
            const size_t ga = ((size_t)(brow0 + ch * 16 + lrow)) * KP + k0 + lcol;
            const size_t gb = ((size_t)(bcol0 + ch * 16 + lrow)) * KP + k0 + lcol;
            __builtin_amdgcn_global_load_lds((gvoid_t*)(g_Fh + ga), (lvoid_t*)(Ah + ldso), 16, 0, 0);
            __builtin_amdgcn_global_load_lds((gvoid_t*)(g_Fl + ga), (lvoid_t*)(Al + ldso), 16, 0, 0);
            __builtin_amdgcn_global_load_lds((gvoid_t*)(g_Ch + gb), (lvoid_t*)(Bh + ldso), 16, 0, 0);
            __builtin_amdgcn_global_load_lds((gvoid_t*)(g_Cl + gb), (lvoid_t*)(Bl + ldso), 16, 0, 0);
        }
        __syncthreads();

        const int arow = wr * 64 + (lane & 15);
        const int brow = wc * 64 + (lane & 15);
        const int kof  = (((lane >> 4) ^ ((lane >> 1) & 3)) * 8);
        bf16x8 afh[4], afl[4], bfh[4], bfl[4];
#pragma unroll
        for (int m = 0; m < 4; ++m){
            afh[m] = *(const bf16x8*)&Ah[(arow + m * 16) * 32 + kof];
            afl[m] = *(const bf16x8*)&Al[(arow + m * 16) * 32 + kof];
        }
#pragma unroll
        for (int n = 0; n < 4; ++n){
            bfh[n] = *(const bf16x8*)&Bh[(brow + n * 16) * 32 + kof];
            bfl[n] = *(const bf16x8*)&Bl[(brow + n * 16) * 32 + kof];
        }
#pragma unroll
        for (int m = 0; m < 4; ++m)
#pragma unroll
            for (int n = 0; n < 4; ++n){
                acc[m][n] = __builtin_amdgcn_mfma_f32_16x16x32_bf16(afh[m], bfh[n], acc[m][n], 0, 0, 0);
                acc[m][n] = __builtin_amdgcn_mfma_f32_16x16x32_bf16(afh[m], bfl[n], acc[m][n], 0, 0, 0);
                acc[m][n] = __builtin_amdgcn_mfma_f32_16x16x32_bf16(afl[m], bfh[n], acc[m][n], 0, 0, 0);
            }
        __syncthreads();
    }

#pragma unroll
    for (int m = 0; m < 4; ++m){
        int rowb = brow0 + wr * 64 + m * 16 + (lane >> 4) * 4;
#pragma unroll
        for (int n = 0; n < 4; ++n){
            int col = bcol0 + wc * 64 + n * 16 + (lane & 15);
            float c2v = g_c2[col];
#pragma unroll
            for (int j = 0; j < 4; ++j){
                float d2 = g_f2[rowb + j] + c2v - 2.0f * acc[m][n][j];
                float d  = sqrtf(fmaxf(d2, 0.0f));
                size_t idx = (size_t)(rowb + j) * NK + col;
                g_dist[idx] = d;
                h16 cv; cv.h = (_Float16)(__expf(-2.0f * d) * 8192.0f);
                g_E[idx] = cv.u;
            }
        }
    }
}

// ---------------- persistent sinkhorn iterations 0..14 (plain cached accesses) ----------------
__global__ __launch_bounds__(256, 4) void cn_sink15(){
    const int lane = threadIdx.x & 63, wid = threadIdx.x >> 6;
    const int gtid = blockIdx.x * 256 + (int)threadIdx.x;
    const int b0 = blockIdx.x * 16 + wid * 4;

    if (gtid < NK){ g_cc[gtid] = 0; g_rc[gtid] = 0; }

    __shared__ float4 sred[3][8][64];
    __shared__ double dred[16][16];

    for (int it = 0; it < 15; ++it){
        const bool useW = (it >= 1);
        const bool f16  = (it <= 9);
        const float cst = (it == 0) ? 1.0f : (1.0f / (float)NB);

        float4 uu[8];
        if (useW){
#pragma unroll
            for (int j = 0; j < 8; ++j)
                uu[j] = *(const float4*)&g_u[4 * lane + 256 * j];
        }

        float4 S[8];
#pragma unroll
        for (int j = 0; j < 8; ++j) S[j] = make_float4(0.f,0.f,0.f,0.f);

        for (int r = 0; r < 4; ++r){
            const int b = b0 + r;
            float tsum = 0.f;
            if (f16){
                ushort4 q4[8];
                const ushort* er = g_E + (size_t)b * NK + 4 * lane;
#pragma unroll
                for (int j = 0; j < 8; ++j){
                    q4[j] = *(const ushort4*)(er + 256 * j);
#pragma unroll
                    for (int c = 0; c < 4; ++c){
                        h16 cv; cv.u = (&q4[j].x)[c];
                        float e = (float)cv.h;
                        tsum += useW ? e * (&uu[j].x)[c] : e;
                    }
                }
#pragma unroll
                for (int off = 32; off; off >>= 1) tsum += __shfl_xor(tsum, off);
                const float v = cst / tsum;
#pragma unroll
                for (int j = 0; j < 8; ++j){
#pragma unroll
                    for (int c = 0; c < 4; ++c){
                        h16 cv; cv.u = (&q4[j].x)[c];
                        (&S[j].x)[c] += (float)cv.h * v;
                    }
                }
            } else {
                float4 ev[8];
                const float* dr = g_dist + (size_t)b * NK + 4 * lane;
#pragma unroll
                for (int j = 0; j < 8; ++j){
                    float4 d4 = *(const float4*)(dr + 256 * j);
#pragma unroll
                    for (int c = 0; c < 4; ++c){
                        float e = __expf(-2.0f * (&d4.x)[c]);
                        (&ev[j].x)[c] = e;
                        tsum += e * (&uu[j].x)[c];
                    }
                }
#pragma unroll
                for (int off = 32; off; off >>= 1) tsum += __shfl_xor(tsum, off);
                const float v = cst / tsum;
#pragma unroll
                for (int j = 0; j < 8; ++j){
                    S[j].x += ev[j].x * v; S[j].y += ev[j].y * v;
                    S[j].z += ev[j].z * v; S[j].w += ev[j].w * v;
                }
            }
        }

        // cross-wave reduce -> block partial (plain vector stores)
        if (wid > 0){
#pragma unroll
            for (int j = 0; j < 8; ++j) sred[wid - 1][j][lane] = S[j];
        }
        __syncthreads();
        if (wid == 0){
#pragma unroll
            for (int w = 0; w < 3; ++w)
#pragma unroll
                for (int j = 0; j < 8; ++j){
                    float4 o = sred[w][j][lane];
                    S[j].x += o.x; S[j].y += o.y; S[j].z += o.z; S[j].w += o.w;
                }
#pragma unroll
            for (int j = 0; j < 8; ++j)
                *(float4*)&g_part[(size_t)blockIdx.x * NK + 4 * lane + 256 * j] = S[j];
        }
        grid_sync();

        // u-reduce: 128 blocks x 16 k's, chunk-major fixed-order fp64 (deterministic)
        if (blockIdx.x < 128){
            const int kq = threadIdx.x & 15;          // k within block tile
            const int cg = threadIdx.x >> 4;          // chunk group 0..15
            const int k = blockIdx.x * 16 + kq;
            double s = 0.0;
#pragma unroll 8
            for (int i = 0; i < 64; ++i)
                s += (double)g_part[(size_t)(cg * 64 + i) * NK + k];
            dred[cg][kq] = s;
            __syncthreads();
            if (threadIdx.x < 16){
                double tot = 0.0;
#pragma unroll
                for (int g = 0; g < 16; ++g) tot += dred[g][threadIdx.x];
                g_u[blockIdx.x * 16 + threadIdx.x] = (float)((1.0 / (double)NK) / tot);
            }
        }
        grid_sync();
    }
}

// ---------------- final sweep: v from u_15, S -> partials; argmax/argmin/loss ----------------
__global__ __launch_bounds__(256) void cn_sweep_fin(float* __restrict__ outba){
    __shared__ float4 sred[3][8][64];
    const int lane = threadIdx.x & 63, wid = threadIdx.x >> 6;
    const int row0 = (blockIdx.x * 4 + wid) * 4;
    const float cst = 1.0f / (float)NB;

    float4 uu[8], ak[8];
#pragma unroll
    for (int j = 0; j < 8; ++j)
        uu[j] = *(const float4*)&g_u[4 * lane + 256 * j];
#pragma unroll
    for (int j = 0; j < 8; ++j)
#pragma unroll
        for (int c = 0; c < 4; ++c)
            (&ak[j].x)[c] = (float)log((double)(&uu[j].x)[c] * (double)NK);

    float4 S[8];
#pragma unroll
    for (int j = 0; j < 8; ++j) S[j] = make_float4(0.f,0.f,0.f,0.f);

    for (int r = 0; r < 4; ++r){
        const int b = row0 + r;
        float4 ev[8], dv[8];
        float tsum = 0.f;
        const float* dr = g_dist + (size_t)b * NK + 4 * lane;
#pragma unroll
        for (int j = 0; j < 8; ++j){
            float4 d4 = *(const float4*)(dr + 256 * j);
#pragma unroll
            for (int c = 0; c < 4; ++c){
                float e = __expf(-2.0f * (&d4.x)[c]);
                (&ev[j].x)[c] = e;
                tsum += e * (&uu[j].x)[c];
            }
            dv[j] = d4;
        }
#pragma unroll
        for (int off = 32; off; off >>= 1) tsum += __shfl_xor(tsum, off);
        const float v = cst / tsum;
#pragma unroll
        for (int j = 0; j < 8; ++j){
            S[j].x += ev[j].x * v; S[j].y += ev[j].y * v;
            S[j].z += ev[j].z * v; S[j].w += ev[j].w * v;
        }

        double bestT = -1.0e300; int bi = 0; float bd = 0.f;
        float rbest = 3.4e38f;   int ri = 0;
#pragma unroll
        for (int j = 0; j < 8; ++j){
#pragma unroll
            for (int c = 0; c < 4; ++c){
                int k = 256 * j + 4 * lane + c;
                float d = (&dv[j].x)[c];
                double t = 2.0 * (double)d - (double)(&ak[j].x)[c];
                if (t > bestT){ bestT = t; bi = k; bd = d; }
                if (d < rbest){ rbest = d; ri = k; }
            }
        }
        for (int off = 32; off; off >>= 1){
            double oT = __shfl_xor(bestT, off);
            int    oi = __shfl_xor(bi, off);
            float  od = __shfl_xor(bd, off);
            if (oT > bestT || (oT == bestT && oi < bi)){ bestT = oT; bi = oi; bd = od; }
            float orb = __shfl_xor(rbest, off);
            int   ori = __shfl_xor(ri, off);
            if (orb < rbest || (orb == rbest && ori < ri)){ rbest = orb; ri = ori; }
        }
        if (lane == 0){
            outba[b] = (float)bi;
            g_bd[b] = bd;
            atomicAdd(&g_cc[bi], 1);
            atomicAdd(&g_rc[ri], 1);
        }
    }

    if (wid > 0){
#pragma unroll
        for (int j = 0; j < 8; ++j) sred[wid - 1][j][lane] = S[j];
    }
    __syncthreads();
    if (wid == 0){
#pragma unroll
        for (int w = 0; w < 3; ++w)
#pragma unroll
            for (int j = 0; j < 8; ++j){
                float4 o = sred[w][j][lane];
                S[j].x += o.x; S[j].y += o.y; S[j].z += o.z; S[j].w += o.w;
            }
#pragma unroll
        for (int j = 0; j < 8; ++j)
            *(float4*)&g_part[(size_t)blockIdx.x * NK + 4 * lane + 256 * j] = S[j];
    }
}

// scnt[k] = B*u[k]*S_k  (fixed-order fp64)
__global__ __launch_bounds__(256) void cn_red_fin(float* __restrict__ out){
    __shared__ double red[4][64];
    const int lane = threadIdx.x & 63, q = threadIdx.x >> 6;
    const int k = blockIdx.x * 64 + lane;
    double s = 0.0;
    for (int ch = q * 256; ch < q * 256 + 256; ++ch)
        s += (double)g_part[(size_t)ch * NK + k];
    red[q][lane] = s;
    __syncthreads();
    if (q == 0){
        double tot = red[0][lane] + red[1][lane] + red[2][lane] + red[3][lane];
        out[1 + NB + k] = (float)((double)NB * (double)g_u[k] * tot);
    }
}

__global__ __launch_bounds__(256) void cn_finalize(float* __restrict__ out){
    int i = blockIdx.x * 256 + threadIdx.x;
    if (i < NK){
        out[1 + NB + NK + i]       = (float)g_cc[i];
        out[1 + NB + 2 * NK + i]   = (float)g_rc[i];
    }
    if (blockIdx.x == 0){
        __shared__ double red[4];
        int lane = threadIdx.x & 63, wid = threadIdx.x >> 6;
        double s = 0.0;
        for (int b = threadIdx.x; b < NB; b += 256) s += (double)g_bd[b];
        for (int off = 32; off; off >>= 1) s += __shfl_xor(s, off);
        if (lane == 0) red[wid] = s;
        __syncthreads();
        if (threadIdx.x == 0)
            out[0] = (float)((red[0] + red[1] + red[2] + red[3]) / (double)NB);
    }
}

extern "C" void kernel_launch(void* const* d_in, const int* in_sizes, int n_in,
                              void* d_out, int out_size, void* d_ws, size_t ws_size,
                              hipStream_t stream){
    const float* F  = (const float*)d_in[0];
    const float* Cn = (const float*)d_in[1];
    float* out = (float*)d_out;
    (void)d_ws; (void)ws_size;

    cn_prep<0><<<NB, 256, 0, stream>>>(F);
    cn_prep<1><<<NK, 256, 0, stream>>>(Cn);

    dim3 gg(NK / 128, NB / 128);
    cn_gemm_dist<<<gg, 256, 0, stream>>>();

    cn_sink15<<<NCHK, 256, 0, stream>>>();

    cn_sweep_fin<<<NCHK, 256, 0, stream>>>(out + 1);
    cn_red_fin<<<NK / 64, 256, 0, stream>>>(out);
    cn_finalize<<<NK / 256, 256, 0, stream>>>(out);
}

// Round 10
// 812.868 us; speedup vs baseline: 6.8244x; 6.0755x over previous
//
#include <hip/hip_runtime.h>

typedef __attribute__((ext_vector_type(8))) short bf16x8;
typedef __attribute__((ext_vector_type(4))) float f32x4;

#define NB 16384
#define NK 2048
#define ND 1000
#define KP 1024            // padded K
#define NCHK 1024          // sinkhorn partial chunks (1 per sweep block)

__device__ float  g_dist[(size_t)NB * NK];          // 128 MiB
__device__ ushort g_E[(size_t)NB * NK];             // 64 MiB fp16 e' = exp(-2d)*8192
__device__ ushort g_Fh[(size_t)NB * KP], g_Fl[(size_t)NB * KP];   // pre-swizzled
__device__ ushort g_Ch[(size_t)NK * KP], g_Cl[(size_t)NK * KP];
__device__ float  g_u[NK], g_c2[NK];
__device__ float  g_f2[NB], g_bd[NB];
__device__ float  g_part[(size_t)NCHK * NK];        // 8 MiB
__device__ int    g_cc[NK], g_rc[NK];

typedef const __attribute__((address_space(1))) void gvoid_t;
typedef __attribute__((address_space(3))) void lvoid_t;

union h16 { ushort u; _Float16 h; };

__device__ __forceinline__ ushort bf16_rne(float x){
    uint u = __float_as_uint(x);
    uint lsb = (u >> 16) & 1u;
    u += 0x7fffu + lsb;
    return (ushort)(u >> 16);
}
__device__ __forceinline__ float bf16_to_f(ushort h){
    return __uint_as_float(((uint)h) << 16);
}

// ---------------- prep: fp32 -> (hi,lo) bf16 split, K-pad, XOR-swizzle, row-sumsq ----------------
template<int WHICH>
__global__ __launch_bounds__(256) void cn_prep(const float* __restrict__ X){
    ushort* __restrict__ H = WHICH ? g_Ch : g_Fh;
    ushort* __restrict__ L = WHICH ? g_Cl : g_Fl;
    float*  __restrict__ sq = WHICH ? g_c2 : g_f2;
    const int row = blockIdx.x, t = threadIdx.x;
    const int lane = t & 63, wid = t >> 6;
    float4 x = make_float4(0.f,0.f,0.f,0.f);
    if (t < 250) x = *(const float4*)(X + (size_t)row * ND + 4 * t);
    double s = (double)x.x*x.x + (double)x.y*x.y + (double)x.z*x.z + (double)x.w*x.w;
    ushort4 h4, l4;
#pragma unroll
    for (int c = 0; c < 4; ++c){
        float xc = (&x.x)[c];
        ushort h = bf16_rne(xc);
        (&h4.x)[c] = h;
        (&l4.x)[c] = bf16_rne(xc - bf16_to_f(h));
    }
    const int base = (t >> 3) << 5;
    const int grp  = (t >> 1) & 3;
    const int pos  = base + ((grp ^ ((row >> 1) & 3)) << 3) + ((4 * t) & 7);
    *(ushort4*)&H[(size_t)row * KP + pos] = h4;
    *(ushort4*)&L[(size_t)row * KP + pos] = l4;

    __shared__ double pr[4];
    for (int off = 32; off; off >>= 1) s += __shfl_xor(s, off);
    if (lane == 0) pr[wid] = s;
    __syncthreads();
    if (t == 0) sq[row] = (float)(pr[0] + pr[1] + pr[2] + pr[3]);
}

// ---------------- split-bf16 MFMA distance GEMM, double-buffered global_load_lds ----------------
// One __syncthreads per K-step: stage(t+1 -> buf^1) issued BEFORE compute(buf),
// the barrier's implicit vmcnt(0) publishes the prefetched buffer.
__global__ __launch_bounds__(256) void cn_gemm_dist(){
    __shared__ __attribute__((aligned(16))) ushort Ah[2][128 * 32];
    __shared__ __attribute__((aligned(16))) ushort Al[2][128 * 32];
    __shared__ __attribute__((aligned(16))) ushort Bh[2][128 * 32];
    __shared__ __attribute__((aligned(16))) ushort Bl[2][128 * 32];

    const int tid = threadIdx.x;
    const int lane = tid & 63, wid = tid >> 6;
    const int wr = wid >> 1, wc = wid & 1;
    const int brow0 = blockIdx.y * 128, bcol0 = blockIdx.x * 128;

    f32x4 acc[4][4];
#pragma unroll
    for (int m = 0; m < 4; ++m)
#pragma unroll
        for (int n = 0; n < 4; ++n) acc[m][n] = (f32x4){0.f,0.f,0.f,0.f};

    const int lrow = lane >> 2;            // 0..15 within 16-row chunk
    const int lcol = (lane & 3) * 8;       // 16B granule within 64B row

#define CN_STAGE(BUF, STEP)                                                             \
    {                                                                                   \
        const int k0_ = (STEP) * 32;                                                    \
        _Pragma("unroll")                                                               \
        for (int i_ = 0; i_ < 2; ++i_){                                                 \
            const int ch_ = wid * 2 + i_;                                               \
            const int ldso_ = ch_ * 512;                                                \
            const size_t ga_ = ((size_t)(brow0 + ch_ * 16 + lrow)) * KP + k0_ + lcol;   \
            const size_t gb_ = ((size_t)(bcol0 + ch_ * 16 + lrow)) * KP + k0_ + lcol;   \
            __builtin_amdgcn_global_load_lds((gvoid_t*)(g_Fh + ga_), (lvoid_t*)(&Ah[BUF][ldso_]), 16, 0, 0); \
            __builtin_amdgcn_global_load_lds((gvoid_t*)(g_Fl + ga_), (lvoid_t*)(&Al[BUF][ldso_]), 16, 0, 0); \
            __builtin_amdgcn_global_load_lds((gvoid_t*)(g_Ch + gb_), (lvoid_t*)(&Bh[BUF][ldso_]), 16, 0, 0); \
            __builtin_amdgcn_global_load_lds((gvoid_t*)(g_Cl + gb_), (lvoid_t*)(&Bl[BUF][ldso_]), 16, 0, 0); \
        }                                                                               \
    }

    CN_STAGE(0, 0)
    __syncthreads();

    const int arow = wr * 64 + (lane & 15);
    const int brow = wc * 64 + (lane & 15);
    const int kof  = (((lane >> 4) ^ ((lane >> 1) & 3)) * 8);   // pre-swizzled layout

    int cur = 0;
    for (int step = 0; step < 32; ++step){
        if (step < 31) CN_STAGE(cur ^ 1, step + 1)

        bf16x8 afh[4], afl[4], bfh[4], bfl[4];
#pragma unroll
        for (int m = 0; m < 4; ++m){
            afh[m] = *(const bf16x8*)&Ah[cur][(arow + m * 16) * 32 + kof];
            afl[m] = *(const bf16x8*)&Al[cur][(arow + m * 16) * 32 + kof];
        }
#pragma unroll
        for (int n = 0; n < 4; ++n){
            bfh[n] = *(const bf16x8*)&Bh[cur][(brow + n * 16) * 32 + kof];
            bfl[n] = *(const bf16x8*)&Bl[cur][(brow + n * 16) * 32 + kof];
        }
#pragma unroll
        for (int m = 0; m < 4; ++m)
#pragma unroll
            for (int n = 0; n < 4; ++n){
                acc[m][n] = __builtin_amdgcn_mfma_f32_16x16x32_bf16(afh[m], bfh[n], acc[m][n], 0, 0, 0);
                acc[m][n] = __builtin_amdgcn_mfma_f32_16x16x32_bf16(afh[m], bfl[n], acc[m][n], 0, 0, 0);
                acc[m][n] = __builtin_amdgcn_mfma_f32_16x16x32_bf16(afl[m], bfh[n], acc[m][n], 0, 0, 0);
            }
        __syncthreads();   // publishes prefetched buffer (implicit vmcnt0) + WAR guard
        cur ^= 1;
    }
#undef CN_STAGE

#pragma unroll
    for (int m = 0; m < 4; ++m){
        int rowb = brow0 + wr * 64 + m * 16 + (lane >> 4) * 4;
#pragma unroll
        for (int n = 0; n < 4; ++n){
            int col = bcol0 + wc * 64 + n * 16 + (lane & 15);
            float c2v = g_c2[col];
#pragma unroll
            for (int j = 0; j < 4; ++j){
                float d2 = g_f2[rowb + j] + c2v - 2.0f * acc[m][n][j];
                float d  = sqrtf(fmaxf(d2, 0.0f));
                size_t idx = (size_t)(rowb + j) * NK + col;
                g_dist[idx] = d;
                h16 cv; cv.h = (_Float16)(__expf(-2.0f * d) * 8192.0f);
                g_E[idx] = cv.u;
            }
        }
    }
}

// ---------------- fused sinkhorn sweep (+ in-block partial reduction) ----------------
// MODE 0: fp16-e first sweep (u==1):  v = 1/T
// MODE 1: fp16-e mid sweep:           v = (1/B)/T,  T = sum e*u
// MODE 2: fp32 mid sweep (exact tail)
// MODE 3: fp32 final sweep + argmax(2d - ln(uK)), argmin d, bd, histograms
template<int MODE>
__global__ __launch_bounds__(256) void cn_sweep(float* __restrict__ outba){
    __shared__ float4 sred[3][8][64];
    const int lane = threadIdx.x & 63, wid = threadIdx.x >> 6;
    const int row0 = (blockIdx.x * 4 + wid) * 4;
    const float cst = (MODE == 0) ? 1.0f : (1.0f / (float)NB);

    float4 uu[8];
    float4 ak[8];
    if (MODE >= 1){
#pragma unroll
        for (int j = 0; j < 8; ++j)
            uu[j] = *(const float4*)&g_u[4 * lane + 256 * j];
    }
    if (MODE == 3){
#pragma unroll
        for (int j = 0; j < 8; ++j)
#pragma unroll
            for (int c = 0; c < 4; ++c)
                (&ak[j].x)[c] = (float)log((double)(&uu[j].x)[c] * (double)NK);
    }

    float4 S[8];
#pragma unroll
    for (int j = 0; j < 8; ++j) S[j] = make_float4(0.f,0.f,0.f,0.f);

    for (int r = 0; r < 4; ++r){
        const int b = row0 + r;
        float4 ev[8];
        float4 dv[8];
        float tsum = 0.f;
        if (MODE <= 1){
            const ushort* er = g_E + (size_t)b * NK + 4 * lane;
#pragma unroll
            for (int j = 0; j < 8; ++j){
                ushort4 q4 = *(const ushort4*)(er + 256 * j);
                float4 e4;
#pragma unroll
                for (int c = 0; c < 4; ++c){
                    h16 cv; cv.u = (&q4.x)[c];
                    float e = (float)cv.h;
                    (&e4.x)[c] = e;
                    tsum += (MODE == 1) ? e * (&uu[j].x)[c] : e;
                }
                ev[j] = e4;
            }
        } else {
            const float* dr = g_dist + (size_t)b * NK + 4 * lane;
#pragma unroll
            for (int j = 0; j < 8; ++j){
                float4 d4 = *(const float4*)(dr + 256 * j);
                float4 e4;
#pragma unroll
                for (int c = 0; c < 4; ++c){
                    float e = __expf(-2.0f * (&d4.x)[c]);
                    (&e4.x)[c] = e;
                    tsum += e * (&uu[j].x)[c];
                }
                ev[j] = e4;
                if (MODE == 3) dv[j] = d4;
            }
        }
#pragma unroll
        for (int off = 32; off; off >>= 1) tsum += __shfl_xor(tsum, off);
        const float v = cst / tsum;
#pragma unroll
        for (int j = 0; j < 8; ++j){
#pragma unroll
            for (int c = 0; c < 4; ++c)
                (&S[j].x)[c] += (&ev[j].x)[c] * v;
        }

        if (MODE == 3){
            double bestT = -1.0e300; int bi = 0; float bd = 0.f;
            float rbest = 3.4e38f;   int ri = 0;
#pragma unroll
            for (int j = 0; j < 8; ++j){
#pragma unroll
                for (int c = 0; c < 4; ++c){
                    int k = 256 * j + 4 * lane + c;
                    float d = (&dv[j].x)[c];
                    double t = 2.0 * (double)d - (double)(&ak[j].x)[c];
                    if (t > bestT){ bestT = t; bi = k; bd = d; }
                    if (d < rbest){ rbest = d; ri = k; }
                }
            }
            for (int off = 32; off; off >>= 1){
                double oT = __shfl_xor(bestT, off);
                int    oi = __shfl_xor(bi, off);
                float  od = __shfl_xor(bd, off);
                if (oT > bestT || (oT == bestT && oi < bi)){ bestT = oT; bi = oi; bd = od; }
                float orb = __shfl_xor(rbest, off);
                int   ori = __shfl_xor(ri, off);
                if (orb < rbest || (orb == rbest && ori < ri)){ rbest = orb; ri = ori; }
            }
            if (lane == 0){
                outba[b] = (float)bi;
                g_bd[b] = bd;
                atomicAdd(&g_cc[bi], 1);
                atomicAdd(&g_rc[ri], 1);
            }
        }
    }

    if (wid > 0){
#pragma unroll
        for (int j = 0; j < 8; ++j) sred[wid - 1][j][lane] = S[j];
    }
    __syncthreads();
    if (wid == 0){
#pragma unroll
        for (int w = 0; w < 3; ++w)
#pragma unroll
            for (int j = 0; j < 8; ++j){
                float4 o = sred[w][j][lane];
                S[j].x += o.x; S[j].y += o.y; S[j].z += o.z; S[j].w += o.w;
            }
#pragma unroll
        for (int j = 0; j < 8; ++j)
            *(float4*)&g_part[(size_t)blockIdx.x * NK + 4 * lane + 256 * j] = S[j];
    }
}

// ---------------- merged partial reduction (fp64, deterministic order) ----------------
// mode 0: u[k] = (1/K)/S_k      mode 1: scnt[k] = B*u[k]*S_k
__global__ __launch_bounds__(256) void cn_red(int mode, float* __restrict__ out){
    __shared__ double red[4][64];
    const int lane = threadIdx.x & 63, q = threadIdx.x >> 6;
    const int k = blockIdx.x * 64 + lane;
    double s = 0.0;
    for (int ch = q * 256; ch < q * 256 + 256; ++ch)
        s += (double)g_part[(size_t)ch * NK + k];
    red[q][lane] = s;
    __syncthreads();
    if (q == 0){
        double tot = red[0][lane] + red[1][lane] + red[2][lane] + red[3][lane];
        if (mode == 0) g_u[k] = (float)((1.0 / (double)NK) / tot);
        else           out[1 + NB + k] = (float)((double)NB * (double)g_u[k] * tot);
    }
}

__global__ __launch_bounds__(256) void cn_zero(){
    int i = blockIdx.x * 256 + threadIdx.x;
    if (i < NK){ g_cc[i] = 0; g_rc[i] = 0; }
}

__global__ __launch_bounds__(256) void cn_finalize(float* __restrict__ out){
    int i = blockIdx.x * 256 + threadIdx.x;
    if (i < NK){
        out[1 + NB + NK + i]       = (float)g_cc[i];
        out[1 + NB + 2 * NK + i]   = (float)g_rc[i];
    }
    if (blockIdx.x == 0){
        __shared__ double red[4];
        int lane = threadIdx.x & 63, wid = threadIdx.x >> 6;
        double s = 0.0;
        for (int b = threadIdx.x; b < NB; b += 256) s += (double)g_bd[b];
        for (int off = 32; off; off >>= 1) s += __shfl_xor(s, off);
        if (lane == 0) red[wid] = s;
        __syncthreads();
        if (threadIdx.x == 0)
            out[0] = (float)((red[0] + red[1] + red[2] + red[3]) / (double)NB);
    }
}

extern "C" void kernel_launch(void* const* d_in, const int* in_sizes, int n_in,
                              void* d_out, int out_size, void* d_ws, size_t ws_size,
                              hipStream_t stream){
    const float* F  = (const float*)d_in[0];
    const float* Cn = (const float*)d_in[1];
    float* out = (float*)d_out;
    (void)d_ws; (void)ws_size;

    cn_prep<0><<<NB, 256, 0, stream>>>(F);
    cn_prep<1><<<NK, 256, 0, stream>>>(Cn);
    cn_zero<<<NK / 256, 256, 0, stream>>>();

    dim3 gg(NK / 128, NB / 128);
    cn_gemm_dist<<<gg, 256, 0, stream>>>();

    // sweep 0 (fp16 e): v0 = 1/rowsum, S(v0) -> u_1
    cn_sweep<0><<<NCHK, 256, 0, stream>>>(nullptr);
    cn_red<<<NK / 64, 256, 0, stream>>>(0, out);

    // sweeps 1..9: fp16 e (noise killed by exact fp32 tail)
    for (int it = 1; it <= 9; ++it){
        cn_sweep<1><<<NCHK, 256, 0, stream>>>(nullptr);
        cn_red<<<NK / 64, 256, 0, stream>>>(0, out);
    }
    // sweeps 10..14: exact fp32 tail
    for (int it = 10; it <= 14; ++it){
        cn_sweep<2><<<NCHK, 256, 0, stream>>>(nullptr);
        cn_red<<<NK / 64, 256, 0, stream>>>(0, out);
    }

    // final sweep: fused assign/argmin/loss; S(v_15) -> scnt
    cn_sweep<3><<<NCHK, 256, 0, stream>>>(out + 1);
    cn_red<<<NK / 64, 256, 0, stream>>>(1, out);

    cn_finalize<<<NK / 256, 256, 0, stream>>>(out);
}

// Round 11
// 762.128 us; speedup vs baseline: 7.2787x; 1.0666x over previous
//
#include <hip/hip_runtime.h>

typedef __attribute__((ext_vector_type(8))) short bf16x8;
typedef __attribute__((ext_vector_type(8))) unsigned short ushort8_t;
typedef __attribute__((ext_vector_type(4))) float f32x4;

#define NB 16384
#define NK 2048
#define ND 1000
#define KP 1024            // padded K
#define NCHK 1024          // sinkhorn partial chunks (1 per sweep block)

__device__ float  g_dist[(size_t)NB * NK];          // 128 MiB
__device__ ushort g_E[(size_t)NB * NK];             // 64 MiB fp16 e' = exp(-2d)*8192
__device__ ushort g_Fh[(size_t)NB * KP], g_Fl[(size_t)NB * KP];   // pre-swizzled
__device__ ushort g_Ch[(size_t)NK * KP], g_Cl[(size_t)NK * KP];
__device__ float  g_u[NK], g_c2[NK];
__device__ float  g_f2[NB], g_bd[NB];
__device__ float  g_part[(size_t)NCHK * NK];        // 8 MiB
__device__ int    g_cc[NK], g_rc[NK];

typedef const __attribute__((address_space(1))) void gvoid_t;
typedef __attribute__((address_space(3))) void lvoid_t;

union h16 { ushort u; _Float16 h; };

__device__ __forceinline__ ushort bf16_rne(float x){
    uint u = __float_as_uint(x);
    uint lsb = (u >> 16) & 1u;
    u += 0x7fffu + lsb;
    return (ushort)(u >> 16);
}
__device__ __forceinline__ float bf16_to_f(ushort h){
    return __uint_as_float(((uint)h) << 16);
}

// ---------------- prep: fp32 -> (hi,lo) bf16 split, K-pad, XOR-swizzle, row-sumsq ----------------
template<int WHICH>
__global__ __launch_bounds__(256) void cn_prep(const float* __restrict__ X){
    ushort* __restrict__ H = WHICH ? g_Ch : g_Fh;
    ushort* __restrict__ L = WHICH ? g_Cl : g_Fl;
    float*  __restrict__ sq = WHICH ? g_c2 : g_f2;
    const int row = blockIdx.x, t = threadIdx.x;
    const int lane = t & 63, wid = t >> 6;
    if (WHICH == 1 && t == 0){ g_cc[row] = 0; g_rc[row] = 0; }   // fold cn_zero in
    float4 x = make_float4(0.f,0.f,0.f,0.f);
    if (t < 250) x = *(const float4*)(X + (size_t)row * ND + 4 * t);
    double s = (double)x.x*x.x + (double)x.y*x.y + (double)x.z*x.z + (double)x.w*x.w;
    ushort4 h4, l4;
#pragma unroll
    for (int c = 0; c < 4; ++c){
        float xc = (&x.x)[c];
        ushort h = bf16_rne(xc);
        (&h4.x)[c] = h;
        (&l4.x)[c] = bf16_rne(xc - bf16_to_f(h));
    }
    const int base = (t >> 3) << 5;
    const int grp  = (t >> 1) & 3;
    const int pos  = base + ((grp ^ ((row >> 1) & 3)) << 3) + ((4 * t) & 7);
    *(ushort4*)&H[(size_t)row * KP + pos] = h4;
    *(ushort4*)&L[(size_t)row * KP + pos] = l4;

    __shared__ double pr[4];
    for (int off = 32; off; off >>= 1) s += __shfl_xor(s, off);
    if (lane == 0) pr[wid] = s;
    __syncthreads();
    if (t == 0) sq[row] = (float)(pr[0] + pr[1] + pr[2] + pr[3]);
}

// ---------------- split-bf16 MFMA distance GEMM (r6 single-buffered, proven 314 us) ----------------
__global__ __launch_bounds__(256) void cn_gemm_dist(){
    __shared__ __attribute__((aligned(16))) ushort Ah[128 * 32];
    __shared__ __attribute__((aligned(16))) ushort Al[128 * 32];
    __shared__ __attribute__((aligned(16))) ushort Bh[128 * 32];
    __shared__ __attribute__((aligned(16))) ushort Bl[128 * 32];

    const int tid = threadIdx.x;
    const int lane = tid & 63, wid = tid >> 6;
    const int wr = wid >> 1, wc = wid & 1;
    const int brow0 = blockIdx.y * 128, bcol0 = blockIdx.x * 128;

    f32x4 acc[4][4];
#pragma unroll
    for (int m = 0; m < 4; ++m)
#pragma unroll
        for (int n = 0; n < 4; ++n) acc[m][n] = (f32x4){0.f,0.f,0.f,0.f};

    const int lrow = lane >> 2;
    const int lcol = (lane & 3) * 8;

    for (int step = 0; step < 32; ++step){
        const int k0 = step * 32;
#pragma unroll
        for (int i = 0; i < 2; ++i){
            const int ch = wid * 2 + i;
            const int ldso = ch * 512;
            const size_t ga = ((size_t)(brow0 + ch * 16 + lrow)) * KP + k0 + lcol;
            const size_t gb = ((size_t)(bcol0 + ch * 16 + lrow)) * KP + k0 + lcol;
            __builtin_amdgcn_global_load_lds((gvoid_t*)(g_Fh + ga), (lvoid_t*)(Ah + ldso), 16, 0, 0);
            __builtin_amdgcn_global_load_lds((gvoid_t*)(g_Fl + ga), (lvoid_t*)(Al + ldso), 16, 0, 0);
            __builtin_amdgcn_global_load_lds((gvoid_t*)(g_Ch + gb), (lvoid_t*)(Bh + ldso), 16, 0, 0);
            __builtin_amdgcn_global_load_lds((gvoid_t*)(g_Cl + gb), (lvoid_t*)(Bl + ldso), 16, 0, 0);
        }
        __syncthreads();

        const int arow = wr * 64 + (lane & 15);
        const int brow = wc * 64 + (lane & 15);
        const int kof  = (((lane >> 4) ^ ((lane >> 1) & 3)) * 8);
        bf16x8 afh[4], afl[4], bfh[4], bfl[4];
#pragma unroll
        for (int m = 0; m < 4; ++m){
            afh[m] = *(const bf16x8*)&Ah[(arow + m * 16) * 32 + kof];
            afl[m] = *(const bf16x8*)&Al[(arow + m * 16) * 32 + kof];
        }
#pragma unroll
        for (int n = 0; n < 4; ++n){
            bfh[n] = *(const bf16x8*)&Bh[(brow + n * 16) * 32 + kof];
            bfl[n] = *(const bf16x8*)&Bl[(brow + n * 16) * 32 + kof];
        }
#pragma unroll
        for (int m = 0; m < 4; ++m)
#pragma unroll
            for (int n = 0; n < 4; ++n){
                acc[m][n] = __builtin_amdgcn_mfma_f32_16x16x32_bf16(afh[m], bfh[n], acc[m][n], 0, 0, 0);
                acc[m][n] = __builtin_amdgcn_mfma_f32_16x16x32_bf16(afh[m], bfl[n], acc[m][n], 0, 0, 0);
                acc[m][n] = __builtin_amdgcn_mfma_f32_16x16x32_bf16(afl[m], bfh[n], acc[m][n], 0, 0, 0);
            }
        __syncthreads();
    }

#pragma unroll
    for (int m = 0; m < 4; ++m){
        int rowb = brow0 + wr * 64 + m * 16 + (lane >> 4) * 4;
#pragma unroll
        for (int n = 0; n < 4; ++n){
            int col = bcol0 + wc * 64 + n * 16 + (lane & 15);
            float c2v = g_c2[col];
#pragma unroll
            for (int j = 0; j < 4; ++j){
                float d2 = g_f2[rowb + j] + c2v - 2.0f * acc[m][n][j];
                float d  = sqrtf(fmaxf(d2, 0.0f));
                size_t idx = (size_t)(rowb + j) * NK + col;
                g_dist[idx] = d;
                h16 cv; cv.h = (_Float16)(__expf(-2.0f * d) * 8192.0f);
                g_E[idx] = cv.u;
            }
        }
    }
}

// ---------------- fused sinkhorn sweep (+ in-block partial reduction) ----------------
// MODE 0: fp16-e first sweep (u==1):  v = 1/T         k-map: 512j + 8*lane + c (16B loads)
// MODE 1: fp16-e mid sweep:           v = (1/B)/T     same k-map
// MODE 2: fp32 mid sweep (exact tail)                 k-map: 256j + 4*lane + c
// MODE 3: fp32 final + argmax(2d - ln(uK)), argmin d, bd, histograms
template<int MODE>
__global__ __launch_bounds__(256) void cn_sweep(float* __restrict__ outba){
    __shared__ float4 sred[3][8][64];
    const int lane = threadIdx.x & 63, wid = threadIdx.x >> 6;
    const int row0 = (blockIdx.x * 4 + wid) * 4;
    const float cst = (MODE == 0) ? 1.0f : (1.0f / (float)NB);

    float4 uu[8];
    float4 ak[8];
    if (MODE == 1){
#pragma unroll
        for (int j = 0; j < 4; ++j)
#pragma unroll
            for (int h = 0; h < 2; ++h)
                uu[2 * j + h] = *(const float4*)&g_u[512 * j + 8 * lane + 4 * h];
    }
    if (MODE >= 2){
#pragma unroll
        for (int j = 0; j < 8; ++j)
            uu[j] = *(const float4*)&g_u[4 * lane + 256 * j];
    }
    if (MODE == 3){
#pragma unroll
        for (int j = 0; j < 8; ++j)
#pragma unroll
            for (int c = 0; c < 4; ++c)
                (&ak[j].x)[c] = (float)log((double)(&uu[j].x)[c] * (double)NK);
    }

    float4 S[8];
#pragma unroll
    for (int j = 0; j < 8; ++j) S[j] = make_float4(0.f,0.f,0.f,0.f);

    for (int r = 0; r < 4; ++r){
        const int b = row0 + r;
        float tsum = 0.f;
        if (MODE <= 1){
            ushort8_t q8[4];
            const ushort* er = g_E + (size_t)b * NK + 8 * lane;
#pragma unroll
            for (int j = 0; j < 4; ++j){
                q8[j] = *(const ushort8_t*)(er + 512 * j);
#pragma unroll
                for (int c = 0; c < 8; ++c){
                    h16 cv; cv.u = q8[j][c];
                    float e = (float)cv.h;
                    tsum += (MODE == 1) ? e * (&uu[2 * j + (c >> 2)].x)[c & 3] : e;
                }
            }
#pragma unroll
            for (int off = 32; off; off >>= 1) tsum += __shfl_xor(tsum, off);
            const float v = cst / tsum;
#pragma unroll
            for (int j = 0; j < 4; ++j)
#pragma unroll
                for (int c = 0; c < 8; ++c){
                    h16 cv; cv.u = q8[j][c];
                    (&S[2 * j + (c >> 2)].x)[c & 3] += (float)cv.h * v;
                }
        } else {
            float4 ev[8], dv[8];
            const float* dr = g_dist + (size_t)b * NK + 4 * lane;
#pragma unroll
            for (int j = 0; j < 8; ++j){
                float4 d4 = *(const float4*)(dr + 256 * j);
#pragma unroll
                for (int c = 0; c < 4; ++c){
                    float e = __expf(-2.0f * (&d4.x)[c]);
                    (&ev[j].x)[c] = e;
                    tsum += e * (&uu[j].x)[c];
                }
                if (MODE == 3) dv[j] = d4;
            }
#pragma unroll
            for (int off = 32; off; off >>= 1) tsum += __shfl_xor(tsum, off);
            const float v = cst / tsum;
#pragma unroll
            for (int j = 0; j < 8; ++j){
                S[j].x += ev[j].x * v; S[j].y += ev[j].y * v;
                S[j].z += ev[j].z * v; S[j].w += ev[j].w * v;
            }

            if (MODE == 3){
                double bestT = -1.0e300; int bi = 0; float bd = 0.f;
                float rbest = 3.4e38f;   int ri = 0;
#pragma unroll
                for (int j = 0; j < 8; ++j){
#pragma unroll
                    for (int c = 0; c < 4; ++c){
                        int k = 256 * j + 4 * lane + c;
                        float d = (&dv[j].x)[c];
                        double t = 2.0 * (double)d - (double)(&ak[j].x)[c];
                        if (t > bestT){ bestT = t; bi = k; bd = d; }
                        if (d < rbest){ rbest = d; ri = k; }
                    }
                }
                for (int off = 32; off; off >>= 1){
                    double oT = __shfl_xor(bestT, off);
                    int    oi = __shfl_xor(bi, off);
                    float  od = __shfl_xor(bd, off);
                    if (oT > bestT || (oT == bestT && oi < bi)){ bestT = oT; bi = oi; bd = od; }
                    float orb = __shfl_xor(rbest, off);
                    int   ori = __shfl_xor(ri, off);
                    if (orb < rbest || (orb == rbest && ori < ri)){ rbest = orb; ri = ori; }
                }
                if (lane == 0){
                    outba[b] = (float)bi;
                    g_bd[b] = bd;
                    atomicAdd(&g_cc[bi], 1);
                    atomicAdd(&g_rc[ri], 1);
                }
            }
        }
    }

    if (wid > 0){
#pragma unroll
        for (int j = 0; j < 8; ++j) sred[wid - 1][j][lane] = S[j];
    }
    __syncthreads();
    if (wid == 0){
#pragma unroll
        for (int w = 0; w < 3; ++w)
#pragma unroll
            for (int j = 0; j < 8; ++j){
                float4 o = sred[w][j][lane];
                S[j].x += o.x; S[j].y += o.y; S[j].z += o.z; S[j].w += o.w;
            }
        if (MODE <= 1){
#pragma unroll
            for (int j = 0; j < 4; ++j)
#pragma unroll
                for (int h = 0; h < 2; ++h)
                    *(float4*)&g_part[(size_t)blockIdx.x * NK + 512 * j + 8 * lane + 4 * h] = S[2 * j + h];
        } else {
#pragma unroll
            for (int j = 0; j < 8; ++j)
                *(float4*)&g_part[(size_t)blockIdx.x * NK + 4 * lane + 256 * j] = S[j];
        }
    }
}

// ---------------- wide u-reduction: 256 blocks, 8 k/block, fixed-order fp64 ----------------
__global__ __launch_bounds__(256) void cn_red0(){
    const int sub = threadIdx.x & 31;
    const int k = blockIdx.x * 8 + (threadIdx.x >> 5);
    double s = 0.0;
#pragma unroll 8
    for (int i = 0; i < 32; ++i)
        s += (double)g_part[(size_t)(i * 32 + sub) * NK + k];
    s += __shfl_xor(s, 16); s += __shfl_xor(s, 8);
    s += __shfl_xor(s, 4);  s += __shfl_xor(s, 2);  s += __shfl_xor(s, 1);
    if (sub == 0) g_u[k] = (float)((1.0 / (double)NK) / s);
}

// ---------------- merged epilogue: scnt + cc/rc + deterministic fp64 loss ----------------
__global__ __launch_bounds__(256) void cn_fin(float* __restrict__ out){
    __shared__ double red[4][64];
    __shared__ double lred[4];
    const int lane = threadIdx.x & 63, q = threadIdx.x >> 6;
    const int k = blockIdx.x * 64 + lane;
    double s = 0.0;
    for (int ch = q * 256; ch < q * 256 + 256; ++ch)
        s += (double)g_part[(size_t)ch * NK + k];
    red[q][lane] = s;
    __syncthreads();
    if (q == 0){
        double tot = red[0][lane] + red[1][lane] + red[2][lane] + red[3][lane];
        out[1 + NB + k] = (float)((double)NB * (double)g_u[k] * tot);
    } else if (q == 1){
        out[1 + NB + NK + k] = (float)g_cc[k];
    } else if (q == 2){
        out[1 + NB + 2 * NK + k] = (float)g_rc[k];
    }
    if (blockIdx.x == 0){
        double sl = 0.0;
        for (int b = threadIdx.x; b < NB; b += 256) sl += (double)g_bd[b];
        for (int off = 32; off; off >>= 1) sl += __shfl_xor(sl, off);
        if (lane == 0) lred[q] = sl;
        __syncthreads();
        if (threadIdx.x == 0)
            out[0] = (float)((lred[0] + lred[1] + lred[2] + lred[3]) / (double)NB);
    }
}

extern "C" void kernel_launch(void* const* d_in, const int* in_sizes, int n_in,
                              void* d_out, int out_size, void* d_ws, size_t ws_size,
                              hipStream_t stream){
    const float* F  = (const float*)d_in[0];
    const float* Cn = (const float*)d_in[1];
    float* out = (float*)d_out;
    (void)d_ws; (void)ws_size;

    cn_prep<0><<<NB, 256, 0, stream>>>(F);
    cn_prep<1><<<NK, 256, 0, stream>>>(Cn);

    dim3 gg(NK / 128, NB / 128);
    cn_gemm_dist<<<gg, 256, 0, stream>>>();

    // it 0: fp16, u==1
    cn_sweep<0><<<NCHK, 256, 0, stream>>>(nullptr);
    cn_red0<<<NK / 8, 256, 0, stream>>>();
    // it 1..11: fp16
    for (int it = 1; it <= 11; ++it){
        cn_sweep<1><<<NCHK, 256, 0, stream>>>(nullptr);
        cn_red0<<<NK / 8, 256, 0, stream>>>();
    }
    // it 12..14: exact fp32 tail
    for (int it = 12; it <= 14; ++it){
        cn_sweep<2><<<NCHK, 256, 0, stream>>>(nullptr);
        cn_red0<<<NK / 8, 256, 0, stream>>>();
    }
    // final sweep: fused assign/argmin/loss; S(v_15) -> scnt partials
    cn_sweep<3><<<NCHK, 256, 0, stream>>>(out + 1);
    cn_fin<<<NK / 64, 256, 0, stream>>>(out);
}

// Round 12
// 722.690 us; speedup vs baseline: 7.6759x; 1.0546x over previous
//
#include <hip/hip_runtime.h>

typedef __attribute__((ext_vector_type(8))) short bf16x8;
typedef __attribute__((ext_vector_type(8))) unsigned short ushort8_t;
typedef __attribute__((ext_vector_type(4))) float f32x4;

#define NB 16384
#define NK 2048
#define ND 1000
#define KP 1024            // padded K
#define NCHK 1024          // sinkhorn partial chunks (1 per sweep block)

__device__ ushort g_E[(size_t)NB * NK];             // 64 MiB fp16 e' = exp(-2d)*8192 (hi)
__device__ ushort g_R[(size_t)NB * NK];             // 64 MiB fp16 residual (e32 - hi)
__device__ ushort g_Fh[(size_t)NB * KP], g_Fl[(size_t)NB * KP];   // pre-swizzled
__device__ ushort g_Ch[(size_t)NK * KP], g_Cl[(size_t)NK * KP];
__device__ float  g_u[NK], g_c2[NK];
__device__ float  g_f2[NB], g_bd[NB];
__device__ float  g_part[(size_t)NCHK * NK];        // 8 MiB
__device__ int    g_cc[NK], g_rc[NK];

typedef const __attribute__((address_space(1))) void gvoid_t;
typedef __attribute__((address_space(3))) void lvoid_t;

union h16 { ushort u; _Float16 h; };

__device__ __forceinline__ ushort bf16_rne(float x){
    uint u = __float_as_uint(x);
    uint lsb = (u >> 16) & 1u;
    u += 0x7fffu + lsb;
    return (ushort)(u >> 16);
}
__device__ __forceinline__ float bf16_to_f(ushort h){
    return __uint_as_float(((uint)h) << 16);
}

// ---------------- prep (merged): fp32 -> (hi,lo) bf16 split, K-pad, XOR-swizzle, row-sumsq ----------------
__global__ __launch_bounds__(256) void cn_prep(const float* __restrict__ F,
                                               const float* __restrict__ Cn){
    const int isC = (blockIdx.x >= NB);
    const int row = isC ? (blockIdx.x - NB) : blockIdx.x;
    const float* __restrict__ X = isC ? Cn : F;
    ushort* __restrict__ H = isC ? g_Ch : g_Fh;
    ushort* __restrict__ L = isC ? g_Cl : g_Fl;
    float*  __restrict__ sq = isC ? g_c2 : g_f2;
    const int t = threadIdx.x;
    const int lane = t & 63, wid = t >> 6;
    if (isC && t == 0){ g_cc[row] = 0; g_rc[row] = 0; }
    float4 x = make_float4(0.f,0.f,0.f,0.f);
    if (t < 250) x = *(const float4*)(X + (size_t)row * ND + 4 * t);
    double s = (double)x.x*x.x + (double)x.y*x.y + (double)x.z*x.z + (double)x.w*x.w;
    ushort4 h4, l4;
#pragma unroll
    for (int c = 0; c < 4; ++c){
        float xc = (&x.x)[c];
        ushort h = bf16_rne(xc);
        (&h4.x)[c] = h;
        (&l4.x)[c] = bf16_rne(xc - bf16_to_f(h));
    }
    const int base = (t >> 3) << 5;
    const int grp  = (t >> 1) & 3;
    const int pos  = base + ((grp ^ ((row >> 1) & 3)) << 3) + ((4 * t) & 7);
    *(ushort4*)&H[(size_t)row * KP + pos] = h4;
    *(ushort4*)&L[(size_t)row * KP + pos] = l4;

    __shared__ double pr[4];
    for (int off = 32; off; off >>= 1) s += __shfl_xor(s, off);
    if (lane == 0) pr[wid] = s;
    __syncthreads();
    if (t == 0) sq[row] = (float)(pr[0] + pr[1] + pr[2] + pr[3]);
}

// ---------------- split-bf16 MFMA distance GEMM (proven single-buffer) ----------------
// epilogue: e32 = exp(-2d)*8192 stored as fp16 hi + fp16 residual (fp32-class recon)
__global__ __launch_bounds__(256) void cn_gemm_dist(){
    __shared__ __attribute__((aligned(16))) ushort Ah[128 * 32];
    __shared__ __attribute__((aligned(16))) ushort Al[128 * 32];
    __shared__ __attribute__((aligned(16))) ushort Bh[128 * 32];
    __shared__ __attribute__((aligned(16))) ushort Bl[128 * 32];

    const int tid = threadIdx.x;
    const int lane = tid & 63, wid = tid >> 6;
    const int wr = wid >> 1, wc = wid & 1;
    const int brow0 = blockIdx.y * 128, bcol0 = blockIdx.x * 128;

    f32x4 acc[4][4];
#pragma unroll
    for (int m = 0; m < 4; ++m)
#pragma unroll
        for (int n = 0; n < 4; ++n) acc[m][n] = (f32x4){0.f,0.f,0.f,0.f};

    const int lrow = lane >> 2;
    const int lcol = (lane & 3) * 8;

    for (int step = 0; step < 32; ++step){
        const int k0 = step * 32;
#pragma unroll
        for (int i = 0; i < 2; ++i){
            const int ch = wid * 2 + i;
            const int ldso = ch * 512;
            const size_t ga = ((size_t)(brow0 + ch * 16 + lrow)) * KP + k0 + lcol;
            const size_t gb = ((size_t)(bcol0 + ch * 16 + lrow)) * KP + k0 + lcol;
            __builtin_amdgcn_global_load_lds((gvoid_t*)(g_Fh + ga), (lvoid_t*)(Ah + ldso), 16, 0, 0);
            __builtin_amdgcn_global_load_lds((gvoid_t*)(g_Fl + ga), (lvoid_t*)(Al + ldso), 16, 0, 0);
            __builtin_amdgcn_global_load_lds((gvoid_t*)(g_Ch + gb), (lvoid_t*)(Bh + ldso), 16, 0, 0);
            __builtin_amdgcn_global_load_lds((gvoid_t*)(g_Cl + gb), (lvoid_t*)(Bl + ldso), 16, 0, 0);
        }
        __syncthreads();

        const int arow = wr * 64 + (lane & 15);
        const int brow = wc * 64 + (lane & 15);
        const int kof  = (((lane >> 4) ^ ((lane >> 1) & 3)) * 8);
        bf16x8 afh[4], afl[4], bfh[4], bfl[4];
#pragma unroll
        for (int m = 0; m < 4; ++m){
            afh[m] = *(const bf16x8*)&Ah[(arow + m * 16) * 32 + kof];
            afl[m] = *(const bf16x8*)&Al[(arow + m * 16) * 32 + kof];
        }
#pragma unroll
        for (int n = 0; n < 4; ++n){
            bfh[n] = *(const bf16x8*)&Bh[(brow + n * 16) * 32 + kof];
            bfl[n] = *(const bf16x8*)&Bl[(brow + n * 16) * 32 + kof];
        }
#pragma unroll
        for (int m = 0; m < 4; ++m)
#pragma unroll
            for (int n = 0; n < 4; ++n){
                acc[m][n] = __builtin_amdgcn_mfma_f32_16x16x32_bf16(afh[m], bfh[n], acc[m][n], 0, 0, 0);
                acc[m][n] = __builtin_amdgcn_mfma_f32_16x16x32_bf16(afh[m], bfl[n], acc[m][n], 0, 0, 0);
                acc[m][n] = __builtin_amdgcn_mfma_f32_16x16x32_bf16(afl[m], bfh[n], acc[m][n], 0, 0, 0);
            }
        __syncthreads();
    }

#pragma unroll
    for (int m = 0; m < 4; ++m){
        int rowb = brow0 + wr * 64 + m * 16 + (lane >> 4) * 4;
#pragma unroll
        for (int n = 0; n < 4; ++n){
            int col = bcol0 + wc * 64 + n * 16 + (lane & 15);
            float c2v = g_c2[col];
#pragma unroll
            for (int j = 0; j < 4; ++j){
                float d2 = g_f2[rowb + j] + c2v - 2.0f * acc[m][n][j];
                float d  = sqrtf(fmaxf(d2, 0.0f));
                float e32 = __expf(-2.0f * d) * 8192.0f;
                size_t idx = (size_t)(rowb + j) * NK + col;
                h16 hv; hv.h = (_Float16)e32;
                float hf = (float)hv.h;
                h16 rv; rv.h = (_Float16)(e32 - hf);
                g_E[idx] = hv.u;
                g_R[idx] = rv.u;
            }
        }
    }
}

// ---------------- fused sinkhorn sweep (+ in-block partial reduction) ----------------
// k-map (all modes): k = 512j + 8*lane + c   (16B ushort8 loads)
// MODE 0: fp16-e first sweep (u==1):  v = 1/T
// MODE 1: fp16-e mid sweep:           v = (1/B)/T,  T = sum e*u
// MODE 2: exact mid sweep: e = h + r  (fp32-class reconstruction)
// MODE 3: exact final + argmin(e*u) [= argmax t], argmax e [= argmin d], bd, histograms
template<int MODE>
__global__ __launch_bounds__(256) void cn_sweep(float* __restrict__ outba){
    __shared__ float4 sred[3][8][64];
    const int lane = threadIdx.x & 63, wid = threadIdx.x >> 6;
    const int row0 = (blockIdx.x * 4 + wid) * 4;
    const float cst = (MODE == 0) ? 1.0f : (1.0f / (float)NB);

    float4 uu[8];
    if (MODE >= 1){
#pragma unroll
        for (int j = 0; j < 4; ++j)
#pragma unroll
            for (int h = 0; h < 2; ++h)
                uu[2 * j + h] = *(const float4*)&g_u[512 * j + 8 * lane + 4 * h];
    }

    float4 S[8];
#pragma unroll
    for (int j = 0; j < 8; ++j) S[j] = make_float4(0.f,0.f,0.f,0.f);

    for (int r = 0; r < 4; ++r){
        const int b = row0 + r;
        float tsum = 0.f;
        if (MODE <= 1){
            ushort8_t q8[4];
            const ushort* er = g_E + (size_t)b * NK + 8 * lane;
#pragma unroll
            for (int j = 0; j < 4; ++j){
                q8[j] = *(const ushort8_t*)(er + 512 * j);
#pragma unroll
                for (int c = 0; c < 8; ++c){
                    h16 cv; cv.u = q8[j][c];
                    float e = (float)cv.h;
                    tsum += (MODE == 1) ? e * (&uu[2 * j + (c >> 2)].x)[c & 3] : e;
                }
            }
#pragma unroll
            for (int off = 32; off; off >>= 1) tsum += __shfl_xor(tsum, off);
            const float v = cst / tsum;
#pragma unroll
            for (int j = 0; j < 4; ++j)
#pragma unroll
                for (int c = 0; c < 8; ++c){
                    h16 cv; cv.u = q8[j][c];
                    (&S[2 * j + (c >> 2)].x)[c & 3] += (float)cv.h * v;
                }
        } else {
            float ev[4][8];
            const ushort* er = g_E + (size_t)b * NK + 8 * lane;
            const ushort* rr = g_R + (size_t)b * NK + 8 * lane;
#pragma unroll
            for (int j = 0; j < 4; ++j){
                ushort8_t qe = *(const ushort8_t*)(er + 512 * j);
                ushort8_t qr = *(const ushort8_t*)(rr + 512 * j);
#pragma unroll
                for (int c = 0; c < 8; ++c){
                    h16 cv; cv.u = qe[c];
                    h16 rv; rv.u = qr[c];
                    float e = (float)cv.h + (float)rv.h;
                    ev[j][c] = e;
                    tsum += e * (&uu[2 * j + (c >> 2)].x)[c & 3];
                }
            }
#pragma unroll
            for (int off = 32; off; off >>= 1) tsum += __shfl_xor(tsum, off);
            const float v = cst / tsum;
#pragma unroll
            for (int j = 0; j < 4; ++j)
#pragma unroll
                for (int c = 0; c < 8; ++c)
                    (&S[2 * j + (c >> 2)].x)[c & 3] += ev[j][c] * v;

            if (MODE == 3){
                // argmin w = e*u  (== argmax t);  argmax e (== argmin d)
                double bestW = 1.0e300; int bi = 0; float be = 1.f;
                float rbe = -1.f;      int ri = 0;
#pragma unroll
                for (int j = 0; j < 4; ++j){
#pragma unroll
                    for (int c = 0; c < 8; ++c){
                        int k = 512 * j + 8 * lane + c;
                        float e = ev[j][c];
                        double w = (double)e * (double)(&uu[2 * j + (c >> 2)].x)[c & 3];
                        if (w < bestW){ bestW = w; bi = k; be = e; }
                        if (e > rbe){ rbe = e; ri = k; }
                    }
                }
                for (int off = 32; off; off >>= 1){
                    double oW = __shfl_xor(bestW, off);
                    int    oi = __shfl_xor(bi, off);
                    float  oe = __shfl_xor(be, off);
                    if (oW < bestW || (oW == bestW && oi < bi)){ bestW = oW; bi = oi; be = oe; }
                    float ore = __shfl_xor(rbe, off);
                    int   ori = __shfl_xor(ri, off);
                    if (ore > rbe || (ore == rbe && ori < ri)){ rbe = ore; ri = ori; }
                }
                if (lane == 0){
                    outba[b] = (float)bi;
                    // d = -0.5*(ln e - ln 8192)
                    g_bd[b] = (float)(-0.5 * (log((double)be) - 9.010913347279288));
                    atomicAdd(&g_cc[bi], 1);
                    atomicAdd(&g_rc[ri], 1);
                }
            }
        }
    }

    if (wid > 0){
#pragma unroll
        for (int j = 0; j < 8; ++j) sred[wid - 1][j][lane] = S[j];
    }
    __syncthreads();
    if (wid == 0){
#pragma unroll
        for (int w = 0; w < 3; ++w)
#pragma unroll
            for (int j = 0; j < 8; ++j){
                float4 o = sred[w][j][lane];
                S[j].x += o.x; S[j].y += o.y; S[j].z += o.z; S[j].w += o.w;
            }
#pragma unroll
        for (int j = 0; j < 4; ++j)
#pragma unroll
            for (int h = 0; h < 2; ++h)
                *(float4*)&g_part[(size_t)blockIdx.x * NK + 512 * j + 8 * lane + 4 * h] = S[2 * j + h];
    }
}

// ---------------- wide u-reduction: 256 blocks, 8 k/block, coalesced, fixed-order fp64 ----------------
__global__ __launch_bounds__(256) void cn_red0(){
    __shared__ double red[4][8];
    const int kk  = threadIdx.x & 7;          // k within tile (8 consecutive lanes = 32B segment)
    const int sub = threadIdx.x >> 3;         // 0..31 chunk-subgroup
    const int wv  = threadIdx.x >> 6;
    const int k = blockIdx.x * 8 + kk;
    double s = 0.0;
#pragma unroll 8
    for (int i = 0; i < 32; ++i)
        s += (double)g_part[(size_t)(i * 32 + sub) * NK + k];
    // butterfly over sub_local = (lane>>3) in {0..7}: lane-xor 8,16,32
    s += __shfl_xor(s, 8); s += __shfl_xor(s, 16); s += __shfl_xor(s, 32);
    if ((threadIdx.x & 63) < 8) red[wv][kk] = s;
    __syncthreads();
    if (threadIdx.x < 8){
        double tot = red[0][kk] + red[1][kk] + red[2][kk] + red[3][kk];
        g_u[blockIdx.x * 8 + kk] = (float)((1.0 / (double)NK) / tot);
    }
}

// ---------------- merged epilogue: scnt + cc/rc + deterministic fp64 loss ----------------
__global__ __launch_bounds__(256) void cn_fin(float* __restrict__ out){
    __shared__ double red[4][64];
    __shared__ double lred[4];
    const int lane = threadIdx.x & 63, q = threadIdx.x >> 6;
    const int k = blockIdx.x * 64 + lane;
    double s = 0.0;
    for (int ch = q * 256; ch < q * 256 + 256; ++ch)
        s += (double)g_part[(size_t)ch * NK + k];
    red[q][lane] = s;
    __syncthreads();
    if (q == 0){
        double tot = red[0][lane] + red[1][lane] + red[2][lane] + red[3][lane];
        out[1 + NB + k] = (float)((double)NB * (double)g_u[k] * tot);
    } else if (q == 1){
        out[1 + NB + NK + k] = (float)g_cc[k];
    } else if (q == 2){
        out[1 + NB + 2 * NK + k] = (float)g_rc[k];
    }
    if (blockIdx.x == 0){
        double sl = 0.0;
        for (int b = threadIdx.x; b < NB; b += 256) sl += (double)g_bd[b];
        for (int off = 32; off; off >>= 1) sl += __shfl_xor(sl, off);
        if (lane == 0) lred[q] = sl;
        __syncthreads();
        if (threadIdx.x == 0)
            out[0] = (float)((lred[0] + lred[1] + lred[2] + lred[3]) / (double)NB);
    }
}

extern "C" void kernel_launch(void* const* d_in, const int* in_sizes, int n_in,
                              void* d_out, int out_size, void* d_ws, size_t ws_size,
                              hipStream_t stream){
    const float* F  = (const float*)d_in[0];
    const float* Cn = (const float*)d_in[1];
    float* out = (float*)d_out;
    (void)d_ws; (void)ws_size;

    cn_prep<<<NB + NK, 256, 0, stream>>>(F, Cn);

    dim3 gg(NK / 128, NB / 128);
    cn_gemm_dist<<<gg, 256, 0, stream>>>();

    // it 0: fp16, u==1
    cn_sweep<0><<<NCHK, 256, 0, stream>>>(nullptr);
    cn_red0<<<NK / 8, 256, 0, stream>>>();
    // it 1..11: fp16
    for (int it = 1; it <= 11; ++it){
        cn_sweep<1><<<NCHK, 256, 0, stream>>>(nullptr);
        cn_red0<<<NK / 8, 256, 0, stream>>>();
    }
    // it 12..14: exact (E+R reconstruction) tail
    for (int it = 12; it <= 14; ++it){
        cn_sweep<2><<<NCHK, 256, 0, stream>>>(nullptr);
        cn_red0<<<NK / 8, 256, 0, stream>>>();
    }
    // final sweep: fused assign/argmin/loss; S(v_15) -> scnt partials
    cn_sweep<3><<<NCHK, 256, 0, stream>>>(out + 1);
    cn_fin<<<NK / 64, 256, 0, stream>>>(out);
}

// Round 13
// 704.643 us; speedup vs baseline: 7.8725x; 1.0256x over previous
//
#include <hip/hip_runtime.h>

typedef __attribute__((ext_vector_type(8))) short bf16x8;
typedef __attribute__((ext_vector_type(8))) unsigned short ushort8_t;
typedef __attribute__((ext_vector_type(4))) float f32x4;
typedef __attribute__((ext_vector_type(16))) float f32x16;

#define NB 16384
#define NK 2048
#define ND 1000
#define KP 1024            // padded K
#define NCHK 1024          // sinkhorn partial chunks (1 per sweep block)

__device__ ushort g_E[(size_t)NB * NK];             // 64 MiB fp16 e' = exp(-2d)*8192 (hi)
__device__ ushort g_R[(size_t)NB * NK];             // 64 MiB fp16 residual (e32 - hi)
__device__ ushort g_Fh[(size_t)NB * KP], g_Fl[(size_t)NB * KP];   // pre-swizzled (64k windows)
__device__ ushort g_Ch[(size_t)NK * KP], g_Cl[(size_t)NK * KP];
__device__ float  g_u[NK], g_c2[NK];
__device__ float  g_f2[NB], g_bd[NB];
__device__ float  g_part[(size_t)NCHK * NK];        // 8 MiB
__device__ int    g_cc[NK], g_rc[NK];

typedef const __attribute__((address_space(1))) void gvoid_t;
typedef __attribute__((address_space(3))) void lvoid_t;

union h16 { ushort u; _Float16 h; };

__device__ __forceinline__ ushort bf16_rne(float x){
    uint u = __float_as_uint(x);
    uint lsb = (u >> 16) & 1u;
    u += 0x7fffu + lsb;
    return (ushort)(u >> 16);
}
__device__ __forceinline__ float bf16_to_f(ushort h){
    return __uint_as_float(((uint)h) << 16);
}

// ---------------- prep (merged): fp32 -> (hi,lo) bf16 split, K-pad, row-sumsq ----------------
// Swizzle for BK=64 GEMM tiles: within each 64-col window (8 x 16B granules),
// granule g of row r is stored at g ^ (r & 7)  -> GEMM ds_read_b128 is 2-lanes/bank (free).
__global__ __launch_bounds__(256) void cn_prep(const float* __restrict__ F,
                                               const float* __restrict__ Cn){
    const int isC = (blockIdx.x >= NB);
    const int row = isC ? (blockIdx.x - NB) : blockIdx.x;
    const float* __restrict__ X = isC ? Cn : F;
    ushort* __restrict__ H = isC ? g_Ch : g_Fh;
    ushort* __restrict__ L = isC ? g_Cl : g_Fl;
    float*  __restrict__ sq = isC ? g_c2 : g_f2;
    const int t = threadIdx.x;
    const int lane = t & 63, wid = t >> 6;
    if (isC && t == 0){ g_cc[row] = 0; g_rc[row] = 0; }
    float4 x = make_float4(0.f,0.f,0.f,0.f);
    if (t < 250) x = *(const float4*)(X + (size_t)row * ND + 4 * t);
    double s = (double)x.x*x.x + (double)x.y*x.y + (double)x.z*x.z + (double)x.w*x.w;
    ushort4 h4, l4;
#pragma unroll
    for (int c = 0; c < 4; ++c){
        float xc = (&x.x)[c];
        ushort h = bf16_rne(xc);
        (&h4.x)[c] = h;
        (&l4.x)[c] = bf16_rne(xc - bf16_to_f(h));
    }
    const int base = (t >> 4) << 6;                 // 64-col window
    const int grp  = (t >> 1) & 7;                  // granule 0..7 within window
    const int pos  = base + ((grp ^ (row & 7)) << 3) + ((4 * t) & 7);
    *(ushort4*)&H[(size_t)row * KP + pos] = h4;
    *(ushort4*)&L[(size_t)row * KP + pos] = l4;

    __shared__ double pr[4];
    for (int off = 32; off; off >>= 1) s += __shfl_xor(s, off);
    if (lane == 0) pr[wid] = s;
    __syncthreads();
    if (t == 0) sq[row] = (float)(pr[0] + pr[1] + pr[2] + pr[3]);
}

// ---------------- split-bf16 32x32x16 MFMA distance GEMM, BK=64 single-buffer ----------------
// 128x128 tile, 4 waves (2x2), per-wave 64x64 = 2x2 tiles of 32x32.
// 3-pass split per tile: hh + hl + lh. Epilogue: e32 -> fp16 hi + fp16 residual.
__global__ __launch_bounds__(256) void cn_gemm_dist(){
    __shared__ __attribute__((aligned(16))) ushort Ah[128 * 64];
    __shared__ __attribute__((aligned(16))) ushort Al[128 * 64];
    __shared__ __attribute__((aligned(16))) ushort Bh[128 * 64];
    __shared__ __attribute__((aligned(16))) ushort Bl[128 * 64];

    const int tid = threadIdx.x;
    const int lane = tid & 63, wid = tid >> 6;
    const int wr = wid >> 1, wc = wid & 1;
    const int brow0 = blockIdx.y * 128, bcol0 = blockIdx.x * 128;

    f32x16 acc[2][2];
#pragma unroll
    for (int mt = 0; mt < 2; ++mt)
#pragma unroll
        for (int nt = 0; nt < 2; ++nt)
#pragma unroll
            for (int r = 0; r < 16; ++r) acc[mt][nt][r] = 0.f;

    const int srow = lane >> 3;            // 0..7 row within 8-row chunk
    const int sgr  = lane & 7;             // granule within row

    const int arow = wr * 64 + (lane & 31);
    const int brow = wc * 64 + (lane & 31);
    const int kh   = lane >> 5;            // k-half (0/1)
    const int rx   = lane & 7;             // swizzle key (= row & 7)

    for (int kt = 0; kt < 16; ++kt){
        const int k0 = kt * 64;
        // stage 64 KB: wave w stages chunks [4w,4w+4) of each matrix; 8 rows/chunk,
        // lane-linear 1 KB per gload (dest = base + lane*16, src pre-swizzled).
#pragma unroll
        for (int c4 = 0; c4 < 4; ++c4){
            const int ch = wid * 4 + c4;           // 0..15
            const int ldso = ch * 512;             // ushorts (1 KB)
            const size_t ga = (size_t)(brow0 + ch * 8 + srow) * KP + k0 + sgr * 8;
            const size_t gb = (size_t)(bcol0 + ch * 8 + srow) * KP + k0 + sgr * 8;
            __builtin_amdgcn_global_load_lds((gvoid_t*)(g_Fh + ga), (lvoid_t*)(Ah + ldso), 16, 0, 0);
            __builtin_amdgcn_global_load_lds((gvoid_t*)(g_Fl + ga), (lvoid_t*)(Al + ldso), 16, 0, 0);
            __builtin_amdgcn_global_load_lds((gvoid_t*)(g_Ch + gb), (lvoid_t*)(Bh + ldso), 16, 0, 0);
            __builtin_amdgcn_global_load_lds((gvoid_t*)(g_Cl + gb), (lvoid_t*)(Bl + ldso), 16, 0, 0);
        }
        __syncthreads();

#pragma unroll
        for (int ks = 0; ks < 4; ++ks){
            const int pg = (ks * 2 + kh) ^ rx;     // physical granule (swizzled)
            bf16x8 a_h[2], a_l[2], b_h[2], b_l[2];
#pragma unroll
            for (int mt = 0; mt < 2; ++mt){
                const int ro = (arow + mt * 32) * 64 + pg * 8;
                a_h[mt] = *(const bf16x8*)&Ah[ro];
                a_l[mt] = *(const bf16x8*)&Al[ro];
            }
#pragma unroll
            for (int nt = 0; nt < 2; ++nt){
                const int ro = (brow + nt * 32) * 64 + pg * 8;
                b_h[nt] = *(const bf16x8*)&Bh[ro];
                b_l[nt] = *(const bf16x8*)&Bl[ro];
            }
#pragma unroll
            for (int mt = 0; mt < 2; ++mt)
#pragma unroll
                for (int nt = 0; nt < 2; ++nt){
                    acc[mt][nt] = __builtin_amdgcn_mfma_f32_32x32x16_bf16(a_h[mt], b_h[nt], acc[mt][nt], 0, 0, 0);
                    acc[mt][nt] = __builtin_amdgcn_mfma_f32_32x32x16_bf16(a_h[mt], b_l[nt], acc[mt][nt], 0, 0, 0);
                    acc[mt][nt] = __builtin_amdgcn_mfma_f32_32x32x16_bf16(a_l[mt], b_h[nt], acc[mt][nt], 0, 0, 0);
                }
        }
        __syncthreads();
    }

    // epilogue: C layout (32x32): col = lane&31, row = (reg&3) + 8*(reg>>2) + 4*(lane>>5)
#pragma unroll
    for (int mt = 0; mt < 2; ++mt){
#pragma unroll
        for (int nt = 0; nt < 2; ++nt){
            const int col = bcol0 + wc * 64 + nt * 32 + (lane & 31);
            const float c2v = g_c2[col];
#pragma unroll
            for (int reg = 0; reg < 16; ++reg){
                const int row = brow0 + wr * 64 + mt * 32 + (reg & 3) + 8 * (reg >> 2) + 4 * kh;
                float d2 = g_f2[row] + c2v - 2.0f * acc[mt][nt][reg];
                float d  = sqrtf(fmaxf(d2, 0.0f));
                float e32 = __expf(-2.0f * d) * 8192.0f;
                size_t idx = (size_t)row * NK + col;
                h16 hv; hv.h = (_Float16)e32;
                float hf = (float)hv.h;
                h16 rv; rv.h = (_Float16)(e32 - hf);
                g_E[idx] = hv.u;
                g_R[idx] = rv.u;
            }
        }
    }
}

// ---------------- fused sinkhorn sweep (+ in-block partial reduction) ----------------
// k-map (all modes): k = 512j + 8*lane + c   (16B ushort8 loads)
// MODE 0: fp16-e first sweep (u==1):  v = 1/T
// MODE 1: fp16-e mid sweep:           v = (1/B)/T,  T = sum e*u
// MODE 2: exact mid sweep: e = h + r  (fp32-class reconstruction)
// MODE 3: exact final + argmin(e*u) [= argmax t], argmax e [= argmin d], bd, histograms
template<int MODE>
__global__ __launch_bounds__(256) void cn_sweep(float* __restrict__ outba){
    __shared__ float4 sred[3][8][64];
    const int lane = threadIdx.x & 63, wid = threadIdx.x >> 6;
    const int row0 = (blockIdx.x * 4 + wid) * 4;
    const float cst = (MODE == 0) ? 1.0f : (1.0f / (float)NB);

    float4 uu[8];
    if (MODE >= 1){
#pragma unroll
        for (int j = 0; j < 4; ++j)
#pragma unroll
            for (int h = 0; h < 2; ++h)
                uu[2 * j + h] = *(const float4*)&g_u[512 * j + 8 * lane + 4 * h];
    }

    float4 S[8];
#pragma unroll
    for (int j = 0; j < 8; ++j) S[j] = make_float4(0.f,0.f,0.f,0.f);

    for (int r = 0; r < 4; ++r){
        const int b = row0 + r;
        float tsum = 0.f;
        if (MODE <= 1){
            ushort8_t q8[4];
            const ushort* er = g_E + (size_t)b * NK + 8 * lane;
#pragma unroll
            for (int j = 0; j < 4; ++j){
                q8[j] = *(const ushort8_t*)(er + 512 * j);
#pragma unroll
                for (int c = 0; c < 8; ++c){
                    h16 cv; cv.u = q8[j][c];
                    float e = (float)cv.h;
                    tsum += (MODE == 1) ? e * (&uu[2 * j + (c >> 2)].x)[c & 3] : e;
                }
            }
#pragma unroll
            for (int off = 32; off; off >>= 1) tsum += __shfl_xor(tsum, off);
            const float v = cst / tsum;
#pragma unroll
            for (int j = 0; j < 4; ++j)
#pragma unroll
                for (int c = 0; c < 8; ++c){
                    h16 cv; cv.u = q8[j][c];
                    (&S[2 * j + (c >> 2)].x)[c & 3] += (float)cv.h * v;
                }
        } else {
            float ev[4][8];
            const ushort* er = g_E + (size_t)b * NK + 8 * lane;
            const ushort* rr = g_R + (size_t)b * NK + 8 * lane;
#pragma unroll
            for (int j = 0; j < 4; ++j){
                ushort8_t qe = *(const ushort8_t*)(er + 512 * j);
                ushort8_t qr = *(const ushort8_t*)(rr + 512 * j);
#pragma unroll
                for (int c = 0; c < 8; ++c){
                    h16 cv; cv.u = qe[c];
                    h16 rv; rv.u = qr[c];
                    float e = (float)cv.h + (float)rv.h;
                    ev[j][c] = e;
                    tsum += e * (&uu[2 * j + (c >> 2)].x)[c & 3];
                }
            }
#pragma unroll
            for (int off = 32; off; off >>= 1) tsum += __shfl_xor(tsum, off);
            const float v = cst / tsum;
#pragma unroll
            for (int j = 0; j < 4; ++j)
#pragma unroll
                for (int c = 0; c < 8; ++c)
                    (&S[2 * j + (c >> 2)].x)[c & 3] += ev[j][c] * v;

            if (MODE == 3){
                double bestW = 1.0e300; int bi = 0; float be = 1.f;
                float rbe = -1.f;      int ri = 0;
#pragma unroll
                for (int j = 0; j < 4; ++j){
#pragma unroll
                    for (int c = 0; c < 8; ++c){
                        int k = 512 * j + 8 * lane + c;
                        float e = ev[j][c];
                        double w = (double)e * (double)(&uu[2 * j + (c >> 2)].x)[c & 3];
                        if (w < bestW){ bestW = w; bi = k; be = e; }
                        if (e > rbe){ rbe = e; ri = k; }
                    }
                }
                for (int off = 32; off; off >>= 1){
                    double oW = __shfl_xor(bestW, off);
                    int    oi = __shfl_xor(bi, off);
                    float  oe = __shfl_xor(be, off);
                    if (oW < bestW || (oW == bestW && oi < bi)){ bestW = oW; bi = oi; be = oe; }
                    float ore = __shfl_xor(rbe, off);
                    int   ori = __shfl_xor(ri, off);
                    if (ore > rbe || (ore == rbe && ori < ri)){ rbe = ore; ri = ori; }
                }
                if (lane == 0){
                    outba[b] = (float)bi;
                    g_bd[b] = (float)(-0.5 * (log((double)be) - 9.010913347279288));
                    atomicAdd(&g_cc[bi], 1);
                    atomicAdd(&g_rc[ri], 1);
                }
            }
        }
    }

    if (wid > 0){
#pragma unroll
        for (int j = 0; j < 8; ++j) sred[wid - 1][j][lane] = S[j];
    }
    __syncthreads();
    if (wid == 0){
#pragma unroll
        for (int w = 0; w < 3; ++w)
#pragma unroll
            for (int j = 0; j < 8; ++j){
                float4 o = sred[w][j][lane];
                S[j].x += o.x; S[j].y += o.y; S[j].z += o.z; S[j].w += o.w;
            }
#pragma unroll
        for (int j = 0; j < 4; ++j)
#pragma unroll
            for (int h = 0; h < 2; ++h)
                *(float4*)&g_part[(size_t)blockIdx.x * NK + 512 * j + 8 * lane + 4 * h] = S[2 * j + h];
    }
}

// ---------------- wide u-reduction: 256 blocks, 8 k/block, coalesced, fixed-order fp64 ----------------
__global__ __launch_bounds__(256) void cn_red0(){
    __shared__ double red[4][8];
    const int kk  = threadIdx.x & 7;
    const int sub = threadIdx.x >> 3;
    const int wv  = threadIdx.x >> 6;
    const int k = blockIdx.x * 8 + kk;
    double s = 0.0;
#pragma unroll 8
    for (int i = 0; i < 32; ++i)
        s += (double)g_part[(size_t)(i * 32 + sub) * NK + k];
    s += __shfl_xor(s, 8); s += __shfl_xor(s, 16); s += __shfl_xor(s, 32);
    if ((threadIdx.x & 63) < 8) red[wv][kk] = s;
    __syncthreads();
    if (threadIdx.x < 8){
        double tot = red[0][kk] + red[1][kk] + red[2][kk] + red[3][kk];
        g_u[blockIdx.x * 8 + kk] = (float)((1.0 / (double)NK) / tot);
    }
}

// ---------------- merged epilogue: scnt + cc/rc + deterministic fp64 loss ----------------
__global__ __launch_bounds__(256) void cn_fin(float* __restrict__ out){
    __shared__ double red[4][64];
    __shared__ double lred[4];
    const int lane = threadIdx.x & 63, q = threadIdx.x >> 6;
    const int k = blockIdx.x * 64 + lane;
    double s = 0.0;
    for (int ch = q * 256; ch < q * 256 + 256; ++ch)
        s += (double)g_part[(size_t)ch * NK + k];
    red[q][lane] = s;
    __syncthreads();
    if (q == 0){
        double tot = red[0][lane] + red[1][lane] + red[2][lane] + red[3][lane];
        out[1 + NB + k] = (float)((double)NB * (double)g_u[k] * tot);
    } else if (q == 1){
        out[1 + NB + NK + k] = (float)g_cc[k];
    } else if (q == 2){
        out[1 + NB + 2 * NK + k] = (float)g_rc[k];
    }
    if (blockIdx.x == 0){
        double sl = 0.0;
        for (int b = threadIdx.x; b < NB; b += 256) sl += (double)g_bd[b];
        for (int off = 32; off; off >>= 1) sl += __shfl_xor(sl, off);
        if (lane == 0) lred[q] = sl;
        __syncthreads();
        if (threadIdx.x == 0)
            out[0] = (float)((lred[0] + lred[1] + lred[2] + lred[3]) / (double)NB);
    }
}

extern "C" void kernel_launch(void* const* d_in, const int* in_sizes, int n_in,
                              void* d_out, int out_size, void* d_ws, size_t ws_size,
                              hipStream_t stream){
    const float* F  = (const float*)d_in[0];
    const float* Cn = (const float*)d_in[1];
    float* out = (float*)d_out;
    (void)d_ws; (void)ws_size;

    cn_prep<<<NB + NK, 256, 0, stream>>>(F, Cn);

    dim3 gg(NK / 128, NB / 128);
    cn_gemm_dist<<<gg, 256, 0, stream>>>();

    // it 0: fp16, u==1
    cn_sweep<0><<<NCHK, 256, 0, stream>>>(nullptr);
    cn_red0<<<NK / 8, 256, 0, stream>>>();
    // it 1..11: fp16
    for (int it = 1; it <= 11; ++it){
        cn_sweep<1><<<NCHK, 256, 0, stream>>>(nullptr);
        cn_red0<<<NK / 8, 256, 0, stream>>>();
    }
    // it 12..14: exact (E+R reconstruction) tail
    for (int it = 12; it <= 14; ++it){
        cn_sweep<2><<<NCHK, 256, 0, stream>>>(nullptr);
        cn_red0<<<NK / 8, 256, 0, stream>>>();
    }
    // final sweep: fused assign/argmin/loss; S(v_15) -> scnt partials
    cn_sweep<3><<<NCHK, 256, 0, stream>>>(out + 1);
    cn_fin<<<NK / 64, 256, 0, stream>>>(out);
}